// Round 2
// baseline (2039.123 us; speedup 1.0000x reference)
//
#include <hip/hip_runtime.h>
#include <cstddef>

#define DIM 128
#define T_LEN 4096
#define BATCH 32
#define L_CH 32
#define N_CH 128                    // T_LEN / L_CH
#define N_CHAINS (BATCH * N_CH)     // 4096

typedef float f32x4 __attribute__((ext_vector_type(4)));
typedef float f32x2 __attribute__((ext_vector_type(2)));

// volatile 16B load: compiler cannot rematerialize -> values pinned in VGPRs
__device__ __forceinline__ f32x4 ld_pin(const float* p) {
    return *reinterpret_cast<const volatile f32x4*>(p);
}

// ---------------- O = X * Y (128x128), row-major (unchanged, tiny) ----------------
__global__ __launch_bounds__(256, 2) void k_mm128(const float* __restrict__ X,
                                                  const float* __restrict__ Y,
                                                  float* __restrict__ O) {
    __shared__ __align__(16) float Ys[DIM][DIM];
    const int t = threadIdx.x;
#pragma unroll
    for (int i = 0; i < 16; ++i) {
        const int j = t + i * 256;
        reinterpret_cast<float4*>(&Ys[0][0])[j] = reinterpret_cast<const float4*>(Y)[j];
    }
    const int r = blockIdx.x * 32 + (t >> 3);
    const int c0 = (t & 7) * 16;
    f32x4 xr[32];
#pragma unroll
    for (int k = 0; k < 32; ++k) xr[k] = ld_pin(&X[r * DIM + 4 * k]);
    __syncthreads();
    float acc[16];
#pragma unroll
    for (int j = 0; j < 16; ++j) acc[j] = 0.f;
#pragma unroll
    for (int k = 0; k < DIM; ++k) {
        const float xv = ((const float*)xr)[k];
#pragma unroll
        for (int j = 0; j < 16; j += 4) {
            const float4 yv = *reinterpret_cast<const float4*>(&Ys[k][c0 + j]);
            acc[j + 0] = fmaf(xv, yv.x, acc[j + 0]);
            acc[j + 1] = fmaf(xv, yv.y, acc[j + 1]);
            acc[j + 2] = fmaf(xv, yv.z, acc[j + 2]);
            acc[j + 3] = fmaf(xv, yv.w, acc[j + 3]);
        }
    }
#pragma unroll
    for (int j = 0; j < 16; j += 4) {
        *reinterpret_cast<float4*>(&O[r * DIM + c0 + j]) =
            make_float4(acc[j], acc[j + 1], acc[j + 2], acc[j + 3]);
    }
}

// ---------------- pass 1: fused B*u + chunk-local scan from 0, emit end state V ----
// 256 threads: thread t -> slice s = t>>6 (32 floats), row pair p = t&63 (rows 2p,2p+1)
__global__ __launch_bounds__(256, 2) void k_scan1(const float* __restrict__ Am,
                                                  const float* __restrict__ Bm,
                                                  const float* __restrict__ u,
                                                  float* __restrict__ V) {
    __shared__ __align__(16) float xs[2][DIM];
    __shared__ __align__(16) float us[2][DIM];
    __shared__ __align__(16) float ps[4][DIM];
    const int t = threadIdx.x;
    const int p = t & 63;
    const int s = t >> 6;
    const int r0 = 2 * p;
    const int chain = blockIdx.x;

    f32x4 a0[8], a1[8], b0[8], b1[8];
    {
        const float* A0 = Am + r0 * DIM + s * 32;
        const float* B0 = Bm + r0 * DIM + s * 32;
#pragma unroll
        for (int j = 0; j < 8; ++j) {
            a0[j] = ld_pin(A0 + 4 * j);
            a1[j] = ld_pin(A0 + DIM + 4 * j);
            b0[j] = ld_pin(B0 + 4 * j);
            b1[j] = ld_pin(B0 + DIM + 4 * j);
        }
    }
    const size_t ubase = (size_t)chain * (L_CH * DIM);
    if (t < DIM) xs[0][t] = 0.f;
    if (t < 32)
        *reinterpret_cast<f32x4*>(&us[0][4 * t]) =
            *reinterpret_cast<const f32x4*>(&u[ubase + 4 * t]);
    __syncthreads();

#pragma unroll 1
    for (int r = 0; r < L_CH; ++r) {
        f32x4 upre;
        const bool pf = (t >= 64 && t < 96) && (r + 1 < L_CH);
        if (pf)
            upre = *reinterpret_cast<const f32x4*>(
                &u[ubase + (size_t)(r + 1) * DIM + 4 * (t - 64)]);
        const float* xsl = &xs[r & 1][s * 32];
        const float* usl = &us[r & 1][s * 32];
        float ax0 = 0.f, ax1 = 0.f, bu0 = 0.f, bu1 = 0.f;
#pragma unroll
        for (int j = 0; j < 8; ++j) {
            const f32x4 xv = *reinterpret_cast<const f32x4*>(xsl + 4 * j);
            const f32x4 uv = *reinterpret_cast<const f32x4*>(usl + 4 * j);
            ax0 = fmaf(a0[j].x, xv.x, ax0); ax0 = fmaf(a0[j].y, xv.y, ax0);
            ax0 = fmaf(a0[j].z, xv.z, ax0); ax0 = fmaf(a0[j].w, xv.w, ax0);
            ax1 = fmaf(a1[j].x, xv.x, ax1); ax1 = fmaf(a1[j].y, xv.y, ax1);
            ax1 = fmaf(a1[j].z, xv.z, ax1); ax1 = fmaf(a1[j].w, xv.w, ax1);
            bu0 = fmaf(b0[j].x, uv.x, bu0); bu0 = fmaf(b0[j].y, uv.y, bu0);
            bu0 = fmaf(b0[j].z, uv.z, bu0); bu0 = fmaf(b0[j].w, uv.w, bu0);
            bu1 = fmaf(b1[j].x, uv.x, bu1); bu1 = fmaf(b1[j].y, uv.y, bu1);
            bu1 = fmaf(b1[j].z, uv.z, bu1); bu1 = fmaf(b1[j].w, uv.w, bu1);
        }
        f32x2 pw; pw.x = ax0 + bu0; pw.y = ax1 + bu1;
        *reinterpret_cast<f32x2*>(&ps[s][r0]) = pw;
        __syncthreads();
        if (t < DIM) {
            const float x1 = (ps[0][t] + ps[1][t]) + (ps[2][t] + ps[3][t]);
            xs[(r + 1) & 1][t] = x1;
            if (r == L_CH - 1) V[(size_t)chain * DIM + t] = x1;
        }
        if (pf)
            *reinterpret_cast<f32x4*>(&us[(r + 1) & 1][4 * (t - 64)]) = upre;
        __syncthreads();
    }
}

// ---------------- boundary combine: s_c = A32 * s_{c-1} + v_{c-1} ----------------
__global__ __launch_bounds__(128, 2) void k_comb(const float* __restrict__ A32,
                                                 const float* __restrict__ V,
                                                 float* __restrict__ S) {
    __shared__ __align__(16) float ss[2][DIM];
    const int i = threadIdx.x;
    const int b = blockIdx.x;
    f32x4 ar[32];
#pragma unroll
    for (int j = 0; j < 32; ++j) ar[j] = ld_pin(&A32[i * DIM + 4 * j]);
    S[(size_t)b * N_CH * DIM + i] = 0.f;
    ss[0][i] = 0.f;
    __syncthreads();
    float vn = V[(size_t)b * N_CH * DIM + i];
#pragma unroll 1
    for (int c = 1; c < N_CH; ++c) {
        float vn_next = 0.f;
        if (c < N_CH - 1) vn_next = V[((size_t)b * N_CH + c) * DIM + i];
        const float* sc = ss[(c - 1) & 1];
        float q0 = 0.f, q1 = 0.f, q2 = 0.f, q3 = 0.f;
#pragma unroll
        for (int j = 0; j < 32; ++j) {
            const f32x4 xv = *reinterpret_cast<const f32x4*>(&sc[4 * j]);
            q0 = fmaf(ar[j].x, xv.x, q0);
            q1 = fmaf(ar[j].y, xv.y, q1);
            q2 = fmaf(ar[j].z, xv.z, q2);
            q3 = fmaf(ar[j].w, xv.w, q3);
        }
        const float s1 = (q0 + q1) + (q2 + q3) + vn;
        vn = vn_next;
        S[((size_t)b * N_CH + c) * DIM + i] = s1;
        ss[c & 1][i] = s1;
        __syncthreads();
    }
}

// ---------------- pass 2 fused: scan from s_c AND y = C x1 + D u, write y only ----
// 512 threads: g = t>>8 (0: state A,B / 1: output C,D), tt = t&255 -> s, row pair
__global__ __launch_bounds__(512, 2) void k_scan3(const float* __restrict__ Am,
                                                  const float* __restrict__ Bm,
                                                  const float* __restrict__ Cm,
                                                  const float* __restrict__ Dm,
                                                  const float* __restrict__ u,
                                                  const float* __restrict__ S,
                                                  float* __restrict__ out) {
    __shared__ __align__(16) float xs[2][DIM];
    __shared__ __align__(16) float us[4][DIM];
    __shared__ __align__(16) float psS[4][DIM];
    __shared__ __align__(16) float psO[4][DIM];
    const int t = threadIdx.x;
    const int g = t >> 8;
    const int tt = t & 255;
    const int p = tt & 63;
    const int s = tt >> 6;
    const int r0 = 2 * p;
    const int chain = blockIdx.x;

    f32x4 m0[8], m1[8], n0[8], n1[8];
    {
        const float* M = (g ? Cm : Am) + r0 * DIM + s * 32;
        const float* N = (g ? Dm : Bm) + r0 * DIM + s * 32;
#pragma unroll
        for (int j = 0; j < 8; ++j) {
            m0[j] = ld_pin(M + 4 * j);
            m1[j] = ld_pin(M + DIM + 4 * j);
            n0[j] = ld_pin(N + 4 * j);
            n1[j] = ld_pin(N + DIM + 4 * j);
        }
    }
    const size_t ubase = (size_t)chain * (L_CH * DIM);
    if (t < DIM) xs[0][t] = S[(size_t)chain * DIM + t];
    if (t < 32)
        *reinterpret_cast<f32x4*>(&us[0][4 * t]) =
            *reinterpret_cast<const f32x4*>(&u[ubase + 4 * t]);
    __syncthreads();

#pragma unroll 1
    for (int r = 0; r < L_CH; ++r) {
        f32x4 upre;
        const bool pf = (t >= 64 && t < 96) && (r + 1 < L_CH);
        if (pf)
            upre = *reinterpret_cast<const f32x4*>(
                &u[ubase + (size_t)(r + 1) * DIM + 4 * (t - 64)]);
        if (g == 0) {
            const float* xsl = &xs[r & 1][s * 32];
            const float* usl = &us[r & 3][s * 32];
            float ax0 = 0.f, ax1 = 0.f, bu0 = 0.f, bu1 = 0.f;
#pragma unroll
            for (int j = 0; j < 8; ++j) {
                const f32x4 xv = *reinterpret_cast<const f32x4*>(xsl + 4 * j);
                const f32x4 uv = *reinterpret_cast<const f32x4*>(usl + 4 * j);
                ax0 = fmaf(m0[j].x, xv.x, ax0); ax0 = fmaf(m0[j].y, xv.y, ax0);
                ax0 = fmaf(m0[j].z, xv.z, ax0); ax0 = fmaf(m0[j].w, xv.w, ax0);
                ax1 = fmaf(m1[j].x, xv.x, ax1); ax1 = fmaf(m1[j].y, xv.y, ax1);
                ax1 = fmaf(m1[j].z, xv.z, ax1); ax1 = fmaf(m1[j].w, xv.w, ax1);
                bu0 = fmaf(n0[j].x, uv.x, bu0); bu0 = fmaf(n0[j].y, uv.y, bu0);
                bu0 = fmaf(n0[j].z, uv.z, bu0); bu0 = fmaf(n0[j].w, uv.w, bu0);
                bu1 = fmaf(n1[j].x, uv.x, bu1); bu1 = fmaf(n1[j].y, uv.y, bu1);
                bu1 = fmaf(n1[j].z, uv.z, bu1); bu1 = fmaf(n1[j].w, uv.w, bu1);
            }
            f32x2 pw; pw.x = ax0 + bu0; pw.y = ax1 + bu1;
            *reinterpret_cast<f32x2*>(&psS[s][r0]) = pw;
        } else if (r >= 1) {
            const float* xsl = &xs[r & 1][s * 32];           // x_r
            const float* usl = &us[(r + 3) & 3][s * 32];     // u_{r-1}
            float cx0 = 0.f, cx1 = 0.f, du0 = 0.f, du1 = 0.f;
#pragma unroll
            for (int j = 0; j < 8; ++j) {
                const f32x4 xv = *reinterpret_cast<const f32x4*>(xsl + 4 * j);
                const f32x4 uv = *reinterpret_cast<const f32x4*>(usl + 4 * j);
                cx0 = fmaf(m0[j].x, xv.x, cx0); cx0 = fmaf(m0[j].y, xv.y, cx0);
                cx0 = fmaf(m0[j].z, xv.z, cx0); cx0 = fmaf(m0[j].w, xv.w, cx0);
                cx1 = fmaf(m1[j].x, xv.x, cx1); cx1 = fmaf(m1[j].y, xv.y, cx1);
                cx1 = fmaf(m1[j].z, xv.z, cx1); cx1 = fmaf(m1[j].w, xv.w, cx1);
                du0 = fmaf(n0[j].x, uv.x, du0); du0 = fmaf(n0[j].y, uv.y, du0);
                du0 = fmaf(n0[j].z, uv.z, du0); du0 = fmaf(n0[j].w, uv.w, du0);
                du1 = fmaf(n1[j].x, uv.x, du1); du1 = fmaf(n1[j].y, uv.y, du1);
                du1 = fmaf(n1[j].z, uv.z, du1); du1 = fmaf(n1[j].w, uv.w, du1);
            }
            f32x2 pw; pw.x = cx0 + du0; pw.y = cx1 + du1;
            *reinterpret_cast<f32x2*>(&psO[s][r0]) = pw;
        }
        __syncthreads();
        if (t < DIM) {
            const float x1 = (psS[0][t] + psS[1][t]) + (psS[2][t] + psS[3][t]);
            xs[(r + 1) & 1][t] = x1;
        } else if (t >= 256 && t < 256 + DIM && r >= 1) {
            const int o = t - 256;
            const float y = (psO[0][o] + psO[1][o]) + (psO[2][o] + psO[3][o]);
            out[ubase + (size_t)(r - 1) * DIM + o] = y;
        }
        if (pf)
            *reinterpret_cast<f32x4*>(&us[(r + 1) & 3][4 * (t - 64)]) = upre;
        __syncthreads();
    }
    // epilogue: y_31 from x_32 (= xs[0]) and u_31 (= us[3])
    if (g == 1) {
        const float* xsl = &xs[0][s * 32];
        const float* usl = &us[3][s * 32];
        float cx0 = 0.f, cx1 = 0.f, du0 = 0.f, du1 = 0.f;
#pragma unroll
        for (int j = 0; j < 8; ++j) {
            const f32x4 xv = *reinterpret_cast<const f32x4*>(xsl + 4 * j);
            const f32x4 uv = *reinterpret_cast<const f32x4*>(usl + 4 * j);
            cx0 = fmaf(m0[j].x, xv.x, cx0); cx0 = fmaf(m0[j].y, xv.y, cx0);
            cx0 = fmaf(m0[j].z, xv.z, cx0); cx0 = fmaf(m0[j].w, xv.w, cx0);
            cx1 = fmaf(m1[j].x, xv.x, cx1); cx1 = fmaf(m1[j].y, xv.y, cx1);
            cx1 = fmaf(m1[j].z, xv.z, cx1); cx1 = fmaf(m1[j].w, xv.w, cx1);
            du0 = fmaf(n0[j].x, uv.x, du0); du0 = fmaf(n0[j].y, uv.y, du0);
            du0 = fmaf(n0[j].z, uv.z, du0); du0 = fmaf(n0[j].w, uv.w, du0);
            du1 = fmaf(n1[j].x, uv.x, du1); du1 = fmaf(n1[j].y, uv.y, du1);
            du1 = fmaf(n1[j].z, uv.z, du1); du1 = fmaf(n1[j].w, uv.w, du1);
        }
        f32x2 pw; pw.x = cx0 + du0; pw.y = cx1 + du1;
        *reinterpret_cast<f32x2*>(&psO[s][r0]) = pw;
    }
    __syncthreads();
    if (t >= 256 && t < 256 + DIM) {
        const int o = t - 256;
        const float y = (psO[0][o] + psO[1][o]) + (psO[2][o] + psO[3][o]);
        out[ubase + (size_t)(L_CH - 1) * DIM + o] = y;
    }
}

extern "C" void kernel_launch(void* const* d_in, const int* in_sizes, int n_in,
                              void* d_out, int out_size, void* d_ws, size_t ws_size,
                              hipStream_t stream) {
    const float* u  = (const float*)d_in[0];   // [32,4096,128]
    const float* Am = (const float*)d_in[1];   // [128,128]
    const float* Bm = (const float*)d_in[2];
    const float* Cm = (const float*)d_in[3];
    const float* Dm = (const float*)d_in[4];
    float* out = (float*)d_out;                // [32,4096,128] fp32

    // ws layout (floats): V | S | A^2 A^4 A^8 A^16 A^32
    float* ws  = (float*)d_ws;
    float* V   = ws;
    float* S   = V + (size_t)N_CHAINS * DIM;
    float* P2  = S + (size_t)N_CHAINS * DIM;
    float* P4  = P2 + DIM * DIM;
    float* P8  = P4 + DIM * DIM;
    float* P16 = P8 + DIM * DIM;
    float* P32 = P16 + DIM * DIM;

    hipLaunchKernelGGL(k_mm128, dim3(4), dim3(256), 0, stream, Am, Am, P2);
    hipLaunchKernelGGL(k_mm128, dim3(4), dim3(256), 0, stream, P2, P2, P4);
    hipLaunchKernelGGL(k_mm128, dim3(4), dim3(256), 0, stream, P4, P4, P8);
    hipLaunchKernelGGL(k_mm128, dim3(4), dim3(256), 0, stream, P8, P8, P16);
    hipLaunchKernelGGL(k_mm128, dim3(4), dim3(256), 0, stream, P16, P16, P32);
    hipLaunchKernelGGL(k_scan1, dim3(N_CHAINS), dim3(256), 0, stream, Am, Bm, u, V);
    hipLaunchKernelGGL(k_comb, dim3(BATCH), dim3(128), 0, stream, P32, V, S);
    hipLaunchKernelGGL(k_scan3, dim3(N_CHAINS), dim3(512), 0, stream,
                       Am, Bm, Cm, Dm, u, S, out);
}

// Round 6
// 403.443 us; speedup vs baseline: 5.0543x; 5.0543x over previous
//
#include <hip/hip_runtime.h>
#include <cstddef>
#include <cstdint>

#define DIM 128
#define T_LEN 4096
#define BATCH 32
#define L_CH 32
#define N_CH 128
#define N_CHAINS 4096            // BATCH * N_CH
#define KFULL 4096               // L_CH * DIM

typedef float f32x4 __attribute__((ext_vector_type(4)));
typedef short s16x8 __attribute__((ext_vector_type(8)));
typedef unsigned short u16x4 __attribute__((ext_vector_type(4)));
typedef unsigned short u16x8 __attribute__((ext_vector_type(8)));
typedef unsigned int u32;

// ---- ws layout (float units) ----
#define OFF_UBF  0               // bf16 [4096][4096]   (8388608 f)
#define OFF_VP   8388608         // f32  [8][4096][128] (4194304 f)
#define OFF_SBF  12582912        // bf16 [4096][128]    (262144 f)
#define OFF_KBF  12845056        // bf16 K[0..31][128][128]  (262144 f)
#define OFF_CABF 13107200        // bf16 CA[0..32][128][128] (270336 f; slot0 unused)
#define OFF_WBF  13377536        // bf16 Wcat [128][4096]    (262144 f)
#define OFF_AP   13639680        // f32 A^d slots d=0..32 (540672 f; slot0 unused)
#define OFF_CA   14180352        // f32 CA[1..32] at slot r-1 (524288 f)
#define OFF_K    14704640        // f32 K[0..31] (524288 f)
#define OFF_W    15228928        // f32 W[0..31] (524288 f; 31 unused)
#define OFF_B    15753216        // f32 copies of B, C, D
#define OFF_C    15769600
#define OFF_D    15785984
#define AP(d)    (OFF_AP + (d) * 16384)

__device__ __forceinline__ f32x4 ld_pin(const float* p) {
    return *reinterpret_cast<const volatile f32x4*>(p);
}
__device__ __forceinline__ unsigned short f2bf(float x) {
    u32 u = __builtin_bit_cast(u32, x);
    return (unsigned short)((u + 0x7FFFu + ((u >> 16) & 1u)) >> 16);
}
__device__ __forceinline__ void gld16(const void* g, void* l) {
    __builtin_amdgcn_global_load_lds((const __attribute__((address_space(1))) u32*)g,
                                     (__attribute__((address_space(3))) u32*)l, 16, 0, 0);
}

// ---------------- copy A,B,C,D into ws (A -> AP[1]) ----------------
__global__ void k_copy4(const float* __restrict__ A, const float* __restrict__ B,
                        const float* __restrict__ C, const float* __restrict__ D,
                        float* __restrict__ wsf) {
    const int e0 = (blockIdx.x * 256 + threadIdx.x) * 4;   // over 65536
    const int mat = e0 >> 14, rem = e0 & 16383;
    const float* src = (mat == 0) ? A : (mat == 1) ? B : (mat == 2) ? C : D;
    const int dst = (mat == 0) ? AP(1) : (mat == 1) ? OFF_B : (mat == 2) ? OFF_C : OFF_D;
    *reinterpret_cast<f32x4*>(wsf + dst + rem) =
        *reinterpret_cast<const f32x4*>(src + rem);
}

// ---------------- u fp32 -> Ubf bf16 (16.7M elems) ----------------
__global__ void k_cast_u(const float* __restrict__ u, unsigned short* __restrict__ ubf) {
    const size_t e0 = (size_t)(blockIdx.x * 256 + threadIdx.x) * 8;
    const f32x4 v0 = *reinterpret_cast<const f32x4*>(u + e0);
    const f32x4 v1 = *reinterpret_cast<const f32x4*>(u + e0 + 4);
    u16x8 o;
    o[0] = f2bf(v0.x); o[1] = f2bf(v0.y); o[2] = f2bf(v0.z); o[3] = f2bf(v0.w);
    o[4] = f2bf(v1.x); o[5] = f2bf(v1.y); o[6] = f2bf(v1.z); o[7] = f2bf(v1.w);
    *reinterpret_cast<u16x8*>(ubf + e0) = o;
}

// ---------------- cast precomputed matrices to bf16 operand layouts ----------------
__global__ void k_castmats(float* __restrict__ wsf) {
    const int e0 = (blockIdx.x * 256 + threadIdx.x) * 4;   // over 1572864
    unsigned short* KBF  = (unsigned short*)(wsf + OFF_KBF);
    unsigned short* CABF = (unsigned short*)(wsf + OFF_CABF);
    unsigned short* WBF  = (unsigned short*)(wsf + OFF_WBF);
    f32x4 v; unsigned short* dst;
    if (e0 < 524288) {                       // K[d] dense
        v = *reinterpret_cast<const f32x4*>(wsf + OFF_K + e0);
        dst = KBF + e0;
    } else if (e0 < 1048576) {               // CA[r], r=1..32 -> CABF slot r
        const int i2 = e0 - 524288;
        v = *reinterpret_cast<const f32x4*>(wsf + OFF_CA + i2);
        dst = CABF + 16384 + i2;
    } else {                                 // Wcat[i][j*128+k'] = W[j][i][k'] ; W[31]=B
        const int widx = e0 - 1048576;
        const int i = widx >> 12, j = (widx >> 7) & 31, kp = widx & 127;
        const int srco = (j == 31) ? (OFF_B + i * 128 + kp)
                                   : (OFF_W + j * 16384 + i * 128 + kp);
        v = *reinterpret_cast<const f32x4*>(wsf + srco);
        dst = WBF + widx;
    }
    u16x4 o; o[0] = f2bf(v.x); o[1] = f2bf(v.y); o[2] = f2bf(v.z); o[3] = f2bf(v.w);
    *reinterpret_cast<u16x4*>(dst) = o;
}

// ---------------- batched 128x128 fp32 matmul: O = X*Y (+Add) ----------------
struct MMDesc { int n; int xo[64]; int yo[64]; int oo[64]; int ao[64]; };

__global__ __launch_bounds__(256, 1) void k_mmb(float* __restrict__ wsf, MMDesc d) {
    const int mm = blockIdx.x >> 2, sub = blockIdx.x & 3;
    const float* X = wsf + d.xo[mm];
    const float* Y = wsf + d.yo[mm];
    float* O = wsf + d.oo[mm];
    const int ao = d.ao[mm];
    __shared__ __align__(16) float Ys[DIM][DIM];
    const int t = threadIdx.x;
#pragma unroll
    for (int i = 0; i < 16; ++i) {
        const int j = t + i * 256;
        reinterpret_cast<f32x4*>(&Ys[0][0])[j] = reinterpret_cast<const f32x4*>(Y)[j];
    }
    const int r = sub * 32 + (t >> 3);
    const int c0 = (t & 7) * 16;
    f32x4 xr[32];
#pragma unroll
    for (int k = 0; k < 32; ++k) xr[k] = ld_pin(&X[r * DIM + 4 * k]);
    __syncthreads();
    float acc[16];
#pragma unroll
    for (int j = 0; j < 16; ++j) acc[j] = 0.f;
#pragma unroll
    for (int k = 0; k < DIM; ++k) {
        const float xv = ((const float*)xr)[k];
#pragma unroll
        for (int j = 0; j < 16; j += 4) {
            const f32x4 yv = *reinterpret_cast<const f32x4*>(&Ys[k][c0 + j]);
            acc[j + 0] = fmaf(xv, yv.x, acc[j + 0]);
            acc[j + 1] = fmaf(xv, yv.y, acc[j + 1]);
            acc[j + 2] = fmaf(xv, yv.z, acc[j + 2]);
            acc[j + 3] = fmaf(xv, yv.w, acc[j + 3]);
        }
    }
    if (ao >= 0) {
        const float* Ad = wsf + ao;
#pragma unroll
        for (int j = 0; j < 16; ++j) acc[j] += Ad[r * DIM + c0 + j];
    }
#pragma unroll
    for (int j = 0; j < 16; j += 4) {
        f32x4 o; o.x = acc[j]; o.y = acc[j + 1]; o.z = acc[j + 2]; o.w = acc[j + 3];
        *reinterpret_cast<f32x4*>(&O[r * DIM + c0 + j]) = o;
    }
}

// ---------------- GEMM1: VP[ksp][m][i] = sum_{k in split} Ubf[m][k] * Wcat[i][k] ----
__global__ __launch_bounds__(256, 2) void k_gemm1(const unsigned short* __restrict__ UBF,
                                                  const unsigned short* __restrict__ WBF,
                                                  float* __restrict__ VP) {
    __shared__ __align__(16) unsigned short lsA[2][4096];
    __shared__ __align__(16) unsigned short lsB[2][4096];
    const int bm = blockIdx.x >> 3, ksp = blockIdx.x & 7;
    const int t = threadIdx.x, w = t >> 6, l = t & 63;
    const int wr = w >> 1, wc = w & 1;
    const int m0 = bm * 128;
    const int rowA0 = w * 32 + (l >> 2);     // staging row, p=0
    const int col8 = (l & 3) * 8;
    const int wvb = w * 1024;                // lds elem base for p=0
    const int kb = ksp * 512;

    f32x4 acc[4][4];
#pragma unroll
    for (int a = 0; a < 4; ++a)
#pragma unroll
        for (int b = 0; b < 4; ++b) acc[a][b] = (f32x4)(0.f);

#define STAGE1(q, buf) do {                                                        \
    const int kq = kb + (q) * 32 + col8;                                           \
    const unsigned short* ga = UBF + (size_t)(m0 + rowA0) * KFULL + kq;            \
    const unsigned short* gb = WBF + (size_t)rowA0 * KFULL + kq;                   \
    gld16(ga, &lsA[buf][wvb]);  gld16(ga + 16 * KFULL, &lsA[buf][wvb + 512]);      \
    gld16(gb, &lsB[buf][wvb]);  gld16(gb + 16 * KFULL, &lsB[buf][wvb + 512]);      \
} while (0)

    STAGE1(0, 0);
    __syncthreads();
#pragma unroll 1
    for (int q = 0; q < 16; ++q) {
        const int buf = q & 1;
        if (q + 1 < 16) STAGE1(q + 1, buf ^ 1);
        s16x8 af[4], bfr[4];
#pragma unroll
        for (int mi = 0; mi < 4; ++mi)
            af[mi] = *(const s16x8*)(&lsA[buf][(wr * 64 + mi * 16 + (l & 15)) * 32 + (l >> 4) * 8]);
#pragma unroll
        for (int ni = 0; ni < 4; ++ni)
            bfr[ni] = *(const s16x8*)(&lsB[buf][(wc * 64 + ni * 16 + (l & 15)) * 32 + (l >> 4) * 8]);
#pragma unroll
        for (int mi = 0; mi < 4; ++mi)
#pragma unroll
            for (int ni = 0; ni < 4; ++ni)
                acc[mi][ni] = __builtin_amdgcn_mfma_f32_16x16x32_bf16(af[mi], bfr[ni], acc[mi][ni], 0, 0, 0);
        __syncthreads();
    }
    float* vp = VP + (size_t)ksp * (N_CHAINS * DIM);
    const int row0 = wr * 64 + (l >> 4) * 4;
    const int col0 = wc * 64 + (l & 15);
#pragma unroll
    for (int mi = 0; mi < 4; ++mi)
#pragma unroll
        for (int ni = 0; ni < 4; ++ni)
#pragma unroll
            for (int jj = 0; jj < 4; ++jj)
                vp[(size_t)(m0 + row0 + mi * 16 + jj) * DIM + col0 + ni * 16] = acc[mi][ni][jj];
#undef STAGE1
}

// ---------------- boundary scan: s_{c} = A32 s_{c-1} + V_{c-1}; write Sbf ----------
__global__ __launch_bounds__(128, 1) void k_comb(const float* __restrict__ wsf_a32,
                                                 const float* __restrict__ VP,
                                                 unsigned short* __restrict__ SBF) {
    __shared__ __align__(16) float xs[DIM];
    const int i = threadIdx.x;
    const int b = blockIdx.x;
    f32x4 ar[32];
#pragma unroll
    for (int j = 0; j < 32; ++j) ar[j] = ld_pin(&wsf_a32[i * DIM + 4 * j]);
    xs[i] = 0.f;
    SBF[(size_t)(b * N_CH) * DIM + i] = 0;
    __syncthreads();
#pragma unroll 1
    for (int c = 1; c < N_CH; ++c) {
        const size_t chp = (size_t)(b * N_CH + c - 1) * DIM + i;
        float v = 0.f;
#pragma unroll
        for (int ksp = 0; ksp < 8; ++ksp) v += VP[(size_t)ksp * (N_CHAINS * DIM) + chp];
        float q0 = 0.f, q1 = 0.f, q2 = 0.f, q3 = 0.f;
#pragma unroll
        for (int j = 0; j < 32; ++j) {
            const f32x4 xv = *reinterpret_cast<const f32x4*>(&xs[4 * j]);
            q0 = fmaf(ar[j].x, xv.x, q0); q1 = fmaf(ar[j].y, xv.y, q1);
            q2 = fmaf(ar[j].z, xv.z, q2); q3 = fmaf(ar[j].w, xv.w, q3);
        }
        const float s1 = (q0 + q1) + (q2 + q3) + v;
        __syncthreads();
        xs[i] = s1;
        SBF[(size_t)(b * N_CH + c) * DIM + i] = f2bf(s1);
        __syncthreads();
    }
}

// ---------------- GEMM3: y tile (bm, r) = sum_{j<=r} U_j K_{r-j}^T + S CA[r+1]^T ----
__global__ __launch_bounds__(256, 2) void k_gemm3(const unsigned short* __restrict__ UBF,
                                                  const unsigned short* __restrict__ SBF,
                                                  const unsigned short* __restrict__ KBF,
                                                  const unsigned short* __restrict__ CABF,
                                                  float* __restrict__ out) {
    __shared__ __align__(16) unsigned short lsA[2][4096];
    __shared__ __align__(16) unsigned short lsB[2][4096];
    const int r = 31 - (blockIdx.x >> 5);
    const int bm = blockIdx.x & 31;
    const int t = threadIdx.x, w = t >> 6, l = t & 63;
    const int wr = w >> 1, wc = w & 1;
    const int m0 = bm * 128;
    const int rowA0 = w * 32 + (l >> 2);
    const int col8 = (l & 3) * 8;
    const int wvb = w * 1024;
    const int NS = 4 * r + 8;

    f32x4 acc[4][4];
#pragma unroll
    for (int a = 0; a < 4; ++a)
#pragma unroll
        for (int b = 0; b < 4; ++b) acc[a][b] = (f32x4)(0.f);

#define STAGE3(q, buf) do {                                                            \
    const int jq = (q) >> 2, kq = ((q) & 3) * 32 + col8;                               \
    const unsigned short *ga, *gb;  int strA, strB;                                    \
    if ((q) < 4 * (r + 1)) {                                                           \
        ga = UBF + (size_t)(m0 + rowA0) * KFULL + jq * 128 + kq;  strA = KFULL;        \
        gb = KBF + (size_t)(r - jq) * 16384 + rowA0 * 128 + kq;   strB = 128;          \
    } else {                                                                           \
        ga = SBF + (size_t)(m0 + rowA0) * 128 + kq;               strA = 128;          \
        gb = CABF + (size_t)(r + 1) * 16384 + rowA0 * 128 + kq;   strB = 128;          \
    }                                                                                  \
    gld16(ga, &lsA[buf][wvb]);  gld16(ga + 16 * strA, &lsA[buf][wvb + 512]);           \
    gld16(gb, &lsB[buf][wvb]);  gld16(gb + 16 * strB, &lsB[buf][wvb + 512]);           \
} while (0)

    STAGE3(0, 0);
    __syncthreads();
#pragma unroll 1
    for (int q = 0; q < NS; ++q) {
        const int buf = q & 1;
        if (q + 1 < NS) STAGE3(q + 1, buf ^ 1);
        s16x8 af[4], bfr[4];
#pragma unroll
        for (int mi = 0; mi < 4; ++mi)
            af[mi] = *(const s16x8*)(&lsA[buf][(wr * 64 + mi * 16 + (l & 15)) * 32 + (l >> 4) * 8]);
#pragma unroll
        for (int ni = 0; ni < 4; ++ni)
            bfr[ni] = *(const s16x8*)(&lsB[buf][(wc * 64 + ni * 16 + (l & 15)) * 32 + (l >> 4) * 8]);
#pragma unroll
        for (int mi = 0; mi < 4; ++mi)
#pragma unroll
            for (int ni = 0; ni < 4; ++ni)
                acc[mi][ni] = __builtin_amdgcn_mfma_f32_16x16x32_bf16(af[mi], bfr[ni], acc[mi][ni], 0, 0, 0);
        __syncthreads();
    }
    const int row0 = wr * 64 + (l >> 4) * 4;
    const int col0 = wc * 64 + (l & 15);
#pragma unroll
    for (int mi = 0; mi < 4; ++mi)
#pragma unroll
        for (int ni = 0; ni < 4; ++ni)
#pragma unroll
            for (int jj = 0; jj < 4; ++jj)
                out[(size_t)(m0 + row0 + mi * 16 + jj) * KFULL + r * 128 + col0 + ni * 16] =
                    acc[mi][ni][jj];
#undef STAGE3
}

extern "C" void kernel_launch(void* const* d_in, const int* in_sizes, int n_in,
                              void* d_out, int out_size, void* d_ws, size_t ws_size,
                              hipStream_t stream) {
    const float* u  = (const float*)d_in[0];
    const float* Am = (const float*)d_in[1];
    const float* Bm = (const float*)d_in[2];
    const float* Cm = (const float*)d_in[3];
    const float* Dm = (const float*)d_in[4];
    float* out = (float*)d_out;
    float* wsf = (float*)d_ws;

    unsigned short* UBF  = (unsigned short*)(wsf + OFF_UBF);
    unsigned short* SBF  = (unsigned short*)(wsf + OFF_SBF);
    unsigned short* KBF  = (unsigned short*)(wsf + OFF_KBF);
    unsigned short* CABF = (unsigned short*)(wsf + OFF_CABF);
    unsigned short* WBF  = (unsigned short*)(wsf + OFF_WBF);
    float* VP = wsf + OFF_VP;

    hipLaunchKernelGGL(k_copy4, dim3(64), dim3(256), 0, stream, Am, Bm, Cm, Dm, wsf);
    hipLaunchKernelGGL(k_cast_u, dim3(8192), dim3(256), 0, stream, u, UBF);

    // power / product stages
    MMDesc s;
    // S1: A2 = A*A
    s.n = 1; s.xo[0] = AP(1); s.yo[0] = AP(1); s.oo[0] = AP(2); s.ao[0] = -1;
    hipLaunchKernelGGL(k_mmb, dim3(4), dim3(256), 0, stream, wsf, s);
    // S2: A3 = A2*A ; A4 = A2*A2
    s.n = 2;
    s.xo[0] = AP(2); s.yo[0] = AP(1); s.oo[0] = AP(3); s.ao[0] = -1;
    s.xo[1] = AP(2); s.yo[1] = AP(2); s.oo[1] = AP(4); s.ao[1] = -1;
    hipLaunchKernelGGL(k_mmb, dim3(8), dim3(256), 0, stream, wsf, s);
    // S3: A5..A8 = A4*A1..A4
    s.n = 4;
    for (int i = 0; i < 4; ++i) { s.xo[i] = AP(4); s.yo[i] = AP(1 + i); s.oo[i] = AP(5 + i); s.ao[i] = -1; }
    hipLaunchKernelGGL(k_mmb, dim3(16), dim3(256), 0, stream, wsf, s);
    // S4: A9..A16 = A8*A1..A8
    s.n = 8;
    for (int i = 0; i < 8; ++i) { s.xo[i] = AP(8); s.yo[i] = AP(1 + i); s.oo[i] = AP(9 + i); s.ao[i] = -1; }
    hipLaunchKernelGGL(k_mmb, dim3(32), dim3(256), 0, stream, wsf, s);
    // S5: A17..A32 = A16*A1..A16
    s.n = 16;
    for (int i = 0; i < 16; ++i) { s.xo[i] = AP(16); s.yo[i] = AP(1 + i); s.oo[i] = AP(17 + i); s.ao[i] = -1; }
    hipLaunchKernelGGL(k_mmb, dim3(64), dim3(256), 0, stream, wsf, s);
    // S6: CA[d] = C*A^d (d=1..32) ; K0 = C*B + D
    s.n = 33;
    for (int i = 0; i < 32; ++i) { s.xo[i] = OFF_C; s.yo[i] = AP(1 + i); s.oo[i] = OFF_CA + i * 16384; s.ao[i] = -1; }
    s.xo[32] = OFF_C; s.yo[32] = OFF_B; s.oo[32] = OFF_K; s.ao[32] = OFF_D;
    hipLaunchKernelGGL(k_mmb, dim3(132), dim3(256), 0, stream, wsf, s);
    // S7: K[d] = CA[d]*B (d=1..31) ; W[j] = A^{31-j}*B (j=0..30)
    s.n = 62;
    for (int i = 0; i < 31; ++i) { s.xo[i] = OFF_CA + i * 16384; s.yo[i] = OFF_B; s.oo[i] = OFF_K + (i + 1) * 16384; s.ao[i] = -1; }
    for (int j = 0; j < 31; ++j) { s.xo[31 + j] = AP(31 - j); s.yo[31 + j] = OFF_B; s.oo[31 + j] = OFF_W + j * 16384; s.ao[31 + j] = -1; }
    hipLaunchKernelGGL(k_mmb, dim3(248), dim3(256), 0, stream, wsf, s);

    hipLaunchKernelGGL(k_castmats, dim3(1536), dim3(256), 0, stream, wsf);
    hipLaunchKernelGGL(k_gemm1, dim3(256), dim3(256), 0, stream, UBF, WBF, VP);
    hipLaunchKernelGGL(k_comb, dim3(BATCH), dim3(128), 0, stream, wsf + AP(32), VP, SBF);
    hipLaunchKernelGGL(k_gemm3, dim3(1024), dim3(256), 0, stream, UBF, SBF, KBF, CABF, out);
}

// Round 7
// 394.875 us; speedup vs baseline: 5.1640x; 1.0217x over previous
//
#include <hip/hip_runtime.h>
#include <cstddef>
#include <cstdint>

#define DIM 128
#define T_LEN 4096
#define BATCH 32
#define L_CH 32
#define N_CH 128
#define N_CHAINS 4096            // BATCH * N_CH
#define KFULL 4096               // L_CH * DIM

typedef float f32x4 __attribute__((ext_vector_type(4)));
typedef short s16x8 __attribute__((ext_vector_type(8)));
typedef unsigned short u16x4 __attribute__((ext_vector_type(4)));
typedef unsigned short u16x8 __attribute__((ext_vector_type(8)));
typedef unsigned int u32;

// ---- ws layout (float units) ----
#define OFF_UBF  0               // bf16 [4096][4096]       (8388608 f)
#define OFF_A64  8388608         // f32 A^64
#define OFF_A96  8404992         // f32 A^96
#define OFF_A128 8421376         // f32 A^128
#define OFF_VBF  8437760         // bf16 [32][136][128] (557056 u16 = 278528 f)
#define OFF_MCBF 8716288         // bf16 Mcat [128][640] (81920 u16 = 40960 f)
#define OFF_SBF  12582912        // bf16 [4096][128]
#define OFF_KBF  12845056        // bf16 K[0..31][128][128]
#define OFF_CABF 13107200        // bf16 CA[0..32][128][128] (slot0 unused)
#define OFF_WBF  13377536        // bf16 Wcat [128][4096]
#define OFF_AP   13639680        // f32 A^d slots d=0..32
#define OFF_CA   14180352        // f32 CA[1..32] at slot r-1
#define OFF_K    14704640        // f32 K[0..31]
#define OFF_W    15228928        // f32 W[0..31]
#define OFF_B    15753216        // f32 copies of B, C, D
#define OFF_C    15769600
#define OFF_D    15785984
#define AP(d)    (OFF_AP + (d) * 16384)

__device__ __forceinline__ f32x4 ld_pin(const float* p) {
    return *reinterpret_cast<const volatile f32x4*>(p);
}
__device__ __forceinline__ unsigned short f2bf(float x) {
    u32 u = __builtin_bit_cast(u32, x);
    return (unsigned short)((u + 0x7FFFu + ((u >> 16) & 1u)) >> 16);
}
__device__ __forceinline__ void gld16(const void* g, void* l) {
    __builtin_amdgcn_global_load_lds((const __attribute__((address_space(1))) u32*)g,
                                     (__attribute__((address_space(3))) u32*)l, 16, 0, 0);
}

// ---------------- fused: u fp32->bf16 cast  +  copy A,B,C,D into ws ----------------
__global__ void k_init(const float* __restrict__ u, const float* __restrict__ A,
                       const float* __restrict__ B, const float* __restrict__ C,
                       const float* __restrict__ D, float* __restrict__ wsf) {
    if (blockIdx.x < 8192) {
        unsigned short* ubf = (unsigned short*)(wsf + OFF_UBF);
        const size_t e0 = (size_t)(blockIdx.x * 256 + threadIdx.x) * 8;
        const f32x4 v0 = *reinterpret_cast<const f32x4*>(u + e0);
        const f32x4 v1 = *reinterpret_cast<const f32x4*>(u + e0 + 4);
        u16x8 o;
        o[0] = f2bf(v0.x); o[1] = f2bf(v0.y); o[2] = f2bf(v0.z); o[3] = f2bf(v0.w);
        o[4] = f2bf(v1.x); o[5] = f2bf(v1.y); o[6] = f2bf(v1.z); o[7] = f2bf(v1.w);
        *reinterpret_cast<u16x8*>(ubf + e0) = o;
    } else {
        const int e0 = ((blockIdx.x - 8192) * 256 + threadIdx.x) * 4;   // over 65536
        const int mat = e0 >> 14, rem = e0 & 16383;
        const float* src = (mat == 0) ? A : (mat == 1) ? B : (mat == 2) ? C : D;
        const int dst = (mat == 0) ? AP(1) : (mat == 1) ? OFF_B : (mat == 2) ? OFF_C : OFF_D;
        *reinterpret_cast<f32x4*>(wsf + dst + rem) =
            *reinterpret_cast<const f32x4*>(src + rem);
    }
}

// ---------------- cast precomputed matrices to bf16 operand layouts ----------------
__global__ void k_castmats(float* __restrict__ wsf) {
    const int e0 = (blockIdx.x * 256 + threadIdx.x) * 4;   // over 1654784
    unsigned short* KBF  = (unsigned short*)(wsf + OFF_KBF);
    unsigned short* CABF = (unsigned short*)(wsf + OFF_CABF);
    unsigned short* WBF  = (unsigned short*)(wsf + OFF_WBF);
    unsigned short* MCBF = (unsigned short*)(wsf + OFF_MCBF);
    u16x4 o;
    unsigned short* dst;
    if (e0 < 524288) {                       // K[d] dense
        const f32x4 v = *reinterpret_cast<const f32x4*>(wsf + OFF_K + e0);
        o[0] = f2bf(v.x); o[1] = f2bf(v.y); o[2] = f2bf(v.z); o[3] = f2bf(v.w);
        dst = KBF + e0;
    } else if (e0 < 1048576) {               // CA[r], r=1..32 -> CABF slot r
        const int i2 = e0 - 524288;
        const f32x4 v = *reinterpret_cast<const f32x4*>(wsf + OFF_CA + i2);
        o[0] = f2bf(v.x); o[1] = f2bf(v.y); o[2] = f2bf(v.z); o[3] = f2bf(v.w);
        dst = CABF + 16384 + i2;
    } else if (e0 < 1572864) {               // Wcat[i][j*128+k'] = W[j][i][k'] ; W[31]=B
        const int widx = e0 - 1048576;
        const int i = widx >> 12, j = (widx >> 7) & 31, kp = widx & 127;
        const int srco = (j == 31) ? (OFF_B + i * 128 + kp)
                                   : (OFF_W + j * 16384 + i * 128 + kp);
        const f32x4 v = *reinterpret_cast<const f32x4*>(wsf + srco);
        o[0] = f2bf(v.x); o[1] = f2bf(v.y); o[2] = f2bf(v.z); o[3] = f2bf(v.w);
        dst = WBF + widx;
    } else {                                 // Mcat[i][e*128+k] = (A^32e)[i][k], e=0..4
        const int mloc = e0 - 1572864;       // over 81920
        const int irow = mloc / 640;
        const int rem  = mloc - irow * 640;
        const int e    = rem >> 7;
        const int k    = rem & 127;
        if (e == 0) {
#pragma unroll
            for (int j = 0; j < 4; ++j)
                o[j] = (k + j == irow) ? (unsigned short)0x3F80 : (unsigned short)0;
        } else {
            const int moff = (e == 1) ? AP(32) : (e == 2) ? OFF_A64
                           : (e == 3) ? OFF_A96 : OFF_A128;
            const f32x4 v = *reinterpret_cast<const f32x4*>(wsf + moff + irow * 128 + k);
            o[0] = f2bf(v.x); o[1] = f2bf(v.y); o[2] = f2bf(v.z); o[3] = f2bf(v.w);
        }
        dst = MCBF + mloc;
    }
    *reinterpret_cast<u16x4*>(dst) = o;
}

// ---------------- batched 128x128 fp32 matmul: O = X*Y (+Add) ----------------
struct MMDesc { int n; int xo[64]; int yo[64]; int oo[64]; int ao[64]; };

__global__ __launch_bounds__(256, 1) void k_mmb(float* __restrict__ wsf, MMDesc d) {
    const int mm = blockIdx.x >> 2, sub = blockIdx.x & 3;
    const float* X = wsf + d.xo[mm];
    const float* Y = wsf + d.yo[mm];
    float* O = wsf + d.oo[mm];
    const int ao = d.ao[mm];
    __shared__ __align__(16) float Ys[DIM][DIM];
    const int t = threadIdx.x;
#pragma unroll
    for (int i = 0; i < 16; ++i) {
        const int j = t + i * 256;
        reinterpret_cast<f32x4*>(&Ys[0][0])[j] = reinterpret_cast<const f32x4*>(Y)[j];
    }
    const int r = sub * 32 + (t >> 3);
    const int c0 = (t & 7) * 16;
    f32x4 xr[32];
#pragma unroll
    for (int k = 0; k < 32; ++k) xr[k] = ld_pin(&X[r * DIM + 4 * k]);
    __syncthreads();
    float acc[16];
#pragma unroll
    for (int j = 0; j < 16; ++j) acc[j] = 0.f;
#pragma unroll
    for (int k = 0; k < DIM; ++k) {
        const float xv = ((const float*)xr)[k];
#pragma unroll
        for (int j = 0; j < 16; j += 4) {
            const f32x4 yv = *reinterpret_cast<const f32x4*>(&Ys[k][c0 + j]);
            acc[j + 0] = fmaf(xv, yv.x, acc[j + 0]);
            acc[j + 1] = fmaf(xv, yv.y, acc[j + 1]);
            acc[j + 2] = fmaf(xv, yv.z, acc[j + 2]);
            acc[j + 3] = fmaf(xv, yv.w, acc[j + 3]);
        }
    }
    if (ao >= 0) {
        const float* Ad = wsf + ao;
#pragma unroll
        for (int j = 0; j < 16; ++j) acc[j] += Ad[r * DIM + c0 + j];
    }
#pragma unroll
    for (int j = 0; j < 16; j += 4) {
        f32x4 o; o.x = acc[j]; o.y = acc[j + 1]; o.z = acc[j + 2]; o.w = acc[j + 3];
        *reinterpret_cast<f32x4*>(&O[r * DIM + c0 + j]) = o;
    }
}

// ---------------- GEMM1: Vbf[b][8+c][i] = bf16( sum_k Ubf[b*128+c][k] * Wcat[i][k] ) -
__global__ __launch_bounds__(256, 2) void k_gemm1(const unsigned short* __restrict__ UBF,
                                                  const unsigned short* __restrict__ WBF,
                                                  unsigned short* __restrict__ VBF) {
    __shared__ __align__(16) unsigned short lsA[2][4096];
    __shared__ __align__(16) unsigned short lsB[2][4096];
    const int b = blockIdx.x;                 // batch 0..31
    const int t = threadIdx.x, w = t >> 6, l = t & 63;
    const int wr = w >> 1, wc = w & 1;
    const int m0 = b * 128;
    const int rowA0 = w * 32 + (l >> 2);
    const int scol8 = ((l & 3) ^ ((l >> 3) & 3)) * 8;   // swizzled source chunk
    const int rsw   = ((l >> 4) ^ ((l >> 1) & 3)) * 8;  // swizzled read chunk
    const int wvb = w * 1024;
    unsigned short* Vb = VBF + b * 17408;
    {   // zero pad rows 0..7 (1024 u16)
        u16x4 z; z[0] = 0; z[1] = 0; z[2] = 0; z[3] = 0;
        *reinterpret_cast<u16x4*>(Vb + t * 4) = z;
    }
    f32x4 acc[4][4];
#pragma unroll
    for (int a = 0; a < 4; ++a)
#pragma unroll
        for (int c = 0; c < 4; ++c) acc[a][c] = (f32x4)(0.f);

#define STAGE1(q, buf) do {                                                        \
    const int kq = (q) * 32 + scol8;                                               \
    const unsigned short* ga = UBF + (size_t)(m0 + rowA0) * KFULL + kq;            \
    const unsigned short* gb = WBF + (size_t)rowA0 * KFULL + kq;                   \
    gld16(ga, &lsA[buf][wvb]);  gld16(ga + 16 * KFULL, &lsA[buf][wvb + 512]);      \
    gld16(gb, &lsB[buf][wvb]);  gld16(gb + 16 * KFULL, &lsB[buf][wvb + 512]);      \
} while (0)

    STAGE1(0, 0);
    __syncthreads();
#pragma unroll 1
    for (int q = 0; q < 128; ++q) {
        const int buf = q & 1;
        if (q + 1 < 128) STAGE1(q + 1, buf ^ 1);
        s16x8 af[4], bfr[4];
#pragma unroll
        for (int mi = 0; mi < 4; ++mi)
            af[mi] = *(const s16x8*)(&lsA[buf][(wr * 64 + mi * 16 + (l & 15)) * 32 + rsw]);
#pragma unroll
        for (int ni = 0; ni < 4; ++ni)
            bfr[ni] = *(const s16x8*)(&lsB[buf][(wc * 64 + ni * 16 + (l & 15)) * 32 + rsw]);
#pragma unroll
        for (int mi = 0; mi < 4; ++mi)
#pragma unroll
            for (int ni = 0; ni < 4; ++ni)
                acc[mi][ni] = __builtin_amdgcn_mfma_f32_16x16x32_bf16(af[mi], bfr[ni], acc[mi][ni], 0, 0, 0);
        __syncthreads();
    }
    const int row0 = wr * 64 + (l >> 4) * 4;
    const int col0 = wc * 64 + (l & 15);
#pragma unroll
    for (int mi = 0; mi < 4; ++mi)
#pragma unroll
        for (int ni = 0; ni < 4; ++ni)
#pragma unroll
            for (int jj = 0; jj < 4; ++jj)
                Vb[(8 + row0 + mi * 16 + jj) * 128 + col0 + ni * 16] = f2bf(acc[mi][ni][jj]);
#undef STAGE1
}

// ---------------- comb2: S[b][c] = sum_{e=0..4} (A^32)^e V[b][c-1-e]  (banded) ------
__global__ __launch_bounds__(256, 2) void k_comb2(const unsigned short* __restrict__ VBF,
                                                  const unsigned short* __restrict__ MCBF,
                                                  unsigned short* __restrict__ SBF) {
    __shared__ __align__(16) unsigned short lsA[2][4096];
    __shared__ __align__(16) unsigned short lsB[2][4096];
    const int b = blockIdx.x;
    const int t = threadIdx.x, w = t >> 6, l = t & 63;
    const int wr = w >> 1, wc = w & 1;
    const int rowA0 = w * 32 + (l >> 2);
    const int scol8 = ((l & 3) ^ ((l >> 3) & 3)) * 8;
    const int rsw   = ((l >> 4) ^ ((l >> 1) & 3)) * 8;
    const int wvb = w * 1024;
    const unsigned short* Vb = VBF + b * 17408;

    f32x4 acc[4][4];
#pragma unroll
    for (int a = 0; a < 4; ++a)
#pragma unroll
        for (int c = 0; c < 4; ++c) acc[a][c] = (f32x4)(0.f);

#define STAGEC(q, buf) do {                                                        \
    const int kq = (q) * 32 + scol8;                                               \
    const int e = kq >> 7, kk = kq & 127;                                          \
    const unsigned short* ga = Vb + (8 + rowA0 - 1 - e) * 128 + kk;                \
    const unsigned short* gb = MCBF + rowA0 * 640 + kq;                            \
    gld16(ga, &lsA[buf][wvb]);  gld16(ga + 16 * 128, &lsA[buf][wvb + 512]);        \
    gld16(gb, &lsB[buf][wvb]);  gld16(gb + 16 * 640, &lsB[buf][wvb + 512]);        \
} while (0)

    STAGEC(0, 0);
    __syncthreads();
#pragma unroll 1
    for (int q = 0; q < 20; ++q) {
        const int buf = q & 1;
        if (q + 1 < 20) STAGEC(q + 1, buf ^ 1);
        s16x8 af[4], bfr[4];
#pragma unroll
        for (int mi = 0; mi < 4; ++mi)
            af[mi] = *(const s16x8*)(&lsA[buf][(wr * 64 + mi * 16 + (l & 15)) * 32 + rsw]);
#pragma unroll
        for (int ni = 0; ni < 4; ++ni)
            bfr[ni] = *(const s16x8*)(&lsB[buf][(wc * 64 + ni * 16 + (l & 15)) * 32 + rsw]);
#pragma unroll
        for (int mi = 0; mi < 4; ++mi)
#pragma unroll
            for (int ni = 0; ni < 4; ++ni)
                acc[mi][ni] = __builtin_amdgcn_mfma_f32_16x16x32_bf16(af[mi], bfr[ni], acc[mi][ni], 0, 0, 0);
        __syncthreads();
    }
    const int row0 = wr * 64 + (l >> 4) * 4;
    const int col0 = wc * 64 + (l & 15);
#pragma unroll
    for (int mi = 0; mi < 4; ++mi)
#pragma unroll
        for (int ni = 0; ni < 4; ++ni)
#pragma unroll
            for (int jj = 0; jj < 4; ++jj)
                SBF[(size_t)(b * 128 + row0 + mi * 16 + jj) * 128 + col0 + ni * 16] =
                    f2bf(acc[mi][ni][jj]);
#undef STAGEC
}

// ---------------- GEMM3: y tile (bm, r) = sum_{j<=r} U_j K_{r-j}^T + S CA[r+1]^T ----
// paired tiles (31-pp, pp): every block does exactly 140 q-steps
__global__ __launch_bounds__(256, 2) void k_gemm3(const unsigned short* __restrict__ UBF,
                                                  const unsigned short* __restrict__ SBF,
                                                  const unsigned short* __restrict__ KBF,
                                                  const unsigned short* __restrict__ CABF,
                                                  float* __restrict__ out) {
    __shared__ __align__(16) unsigned short lsA[2][4096];
    __shared__ __align__(16) unsigned short lsB[2][4096];
    const int pp = blockIdx.x >> 5;          // 0..15
    const int bm = blockIdx.x & 31;
    const int t = threadIdx.x, w = t >> 6, l = t & 63;
    const int wr = w >> 1, wc = w & 1;
    const int m0 = bm * 128;
    const int rowA0 = w * 32 + (l >> 2);
    const int scol8 = ((l & 3) ^ ((l >> 3) & 3)) * 8;
    const int rsw   = ((l >> 4) ^ ((l >> 1) & 3)) * 8;
    const int wvb = w * 1024;
    const int row0 = wr * 64 + (l >> 4) * 4;
    const int col0 = wc * 64 + (l & 15);

#define STAGE3(q, buf) do {                                                            \
    const unsigned short *ga, *gb;  int strA, strB;                                    \
    if ((q) < 4 * (r + 1)) {                                                           \
        ga = UBF + (size_t)(m0 + rowA0) * KFULL + (q) * 32 + scol8;  strA = KFULL;     \
        gb = KBF + (size_t)(r - ((q) >> 2)) * 16384 + rowA0 * 128                      \
             + ((q) & 3) * 32 + scol8;                               strB = 128;       \
    } else {                                                                           \
        ga = SBF + (size_t)(m0 + rowA0) * 128 + ((q) & 3) * 32 + scol8;  strA = 128;   \
        gb = CABF + (size_t)(r + 1) * 16384 + rowA0 * 128 + ((q) & 3) * 32 + scol8;    \
        strB = 128;                                                                    \
    }                                                                                  \
    gld16(ga, &lsA[buf][wvb]);  gld16(ga + 16 * strA, &lsA[buf][wvb + 512]);           \
    gld16(gb, &lsB[buf][wvb]);  gld16(gb + 16 * strB, &lsB[buf][wvb + 512]);           \
} while (0)

#pragma unroll 1
    for (int h = 0; h < 2; ++h) {
        const int r = h ? pp : (31 - pp);
        const int NS = 4 * r + 8;
        f32x4 acc[4][4];
#pragma unroll
        for (int a = 0; a < 4; ++a)
#pragma unroll
            for (int c = 0; c < 4; ++c) acc[a][c] = (f32x4)(0.f);
        STAGE3(0, 0);
        __syncthreads();
#pragma unroll 1
        for (int q = 0; q < NS; ++q) {
            const int buf = q & 1;
            if (q + 1 < NS) STAGE3(q + 1, buf ^ 1);
            s16x8 af[4], bfr[4];
#pragma unroll
            for (int mi = 0; mi < 4; ++mi)
                af[mi] = *(const s16x8*)(&lsA[buf][(wr * 64 + mi * 16 + (l & 15)) * 32 + rsw]);
#pragma unroll
            for (int ni = 0; ni < 4; ++ni)
                bfr[ni] = *(const s16x8*)(&lsB[buf][(wc * 64 + ni * 16 + (l & 15)) * 32 + rsw]);
#pragma unroll
            for (int mi = 0; mi < 4; ++mi)
#pragma unroll
                for (int ni = 0; ni < 4; ++ni)
                    acc[mi][ni] = __builtin_amdgcn_mfma_f32_16x16x32_bf16(af[mi], bfr[ni], acc[mi][ni], 0, 0, 0);
            __syncthreads();
        }
#pragma unroll
        for (int mi = 0; mi < 4; ++mi)
#pragma unroll
            for (int ni = 0; ni < 4; ++ni)
#pragma unroll
                for (int jj = 0; jj < 4; ++jj)
                    out[(size_t)(m0 + row0 + mi * 16 + jj) * KFULL + r * 128 + col0 + ni * 16] =
                        acc[mi][ni][jj];
    }
#undef STAGE3
}

extern "C" void kernel_launch(void* const* d_in, const int* in_sizes, int n_in,
                              void* d_out, int out_size, void* d_ws, size_t ws_size,
                              hipStream_t stream) {
    const float* u  = (const float*)d_in[0];
    const float* Am = (const float*)d_in[1];
    const float* Bm = (const float*)d_in[2];
    const float* Cm = (const float*)d_in[3];
    const float* Dm = (const float*)d_in[4];
    float* out = (float*)d_out;
    float* wsf = (float*)d_ws;

    unsigned short* UBF  = (unsigned short*)(wsf + OFF_UBF);
    unsigned short* SBF  = (unsigned short*)(wsf + OFF_SBF);
    unsigned short* KBF  = (unsigned short*)(wsf + OFF_KBF);
    unsigned short* CABF = (unsigned short*)(wsf + OFF_CABF);
    unsigned short* WBF  = (unsigned short*)(wsf + OFF_WBF);
    unsigned short* VBF  = (unsigned short*)(wsf + OFF_VBF);
    unsigned short* MCBF = (unsigned short*)(wsf + OFF_MCBF);

    hipLaunchKernelGGL(k_init, dim3(8256), dim3(256), 0, stream, u, Am, Bm, Cm, Dm, wsf);

    // power / product stages
    MMDesc s;
    // S1: A2 = A*A
    s.n = 1; s.xo[0] = AP(1); s.yo[0] = AP(1); s.oo[0] = AP(2); s.ao[0] = -1;
    hipLaunchKernelGGL(k_mmb, dim3(4), dim3(256), 0, stream, wsf, s);
    // S2: A3 = A2*A ; A4 = A2*A2
    s.n = 2;
    s.xo[0] = AP(2); s.yo[0] = AP(1); s.oo[0] = AP(3); s.ao[0] = -1;
    s.xo[1] = AP(2); s.yo[1] = AP(2); s.oo[1] = AP(4); s.ao[1] = -1;
    hipLaunchKernelGGL(k_mmb, dim3(8), dim3(256), 0, stream, wsf, s);
    // S3: A5..A8 = A4*A1..A4
    s.n = 4;
    for (int i = 0; i < 4; ++i) { s.xo[i] = AP(4); s.yo[i] = AP(1 + i); s.oo[i] = AP(5 + i); s.ao[i] = -1; }
    hipLaunchKernelGGL(k_mmb, dim3(16), dim3(256), 0, stream, wsf, s);
    // S4: A9..A16 = A8*A1..A8
    s.n = 8;
    for (int i = 0; i < 8; ++i) { s.xo[i] = AP(8); s.yo[i] = AP(1 + i); s.oo[i] = AP(9 + i); s.ao[i] = -1; }
    hipLaunchKernelGGL(k_mmb, dim3(32), dim3(256), 0, stream, wsf, s);
    // S5: A17..A32 = A16*A1..A16
    s.n = 16;
    for (int i = 0; i < 16; ++i) { s.xo[i] = AP(16); s.yo[i] = AP(1 + i); s.oo[i] = AP(17 + i); s.ao[i] = -1; }
    hipLaunchKernelGGL(k_mmb, dim3(64), dim3(256), 0, stream, wsf, s);
    // S6: CA[d] = C*A^d (d=1..32) ; K0 = C*B + D ; A64 = A32*A32
    s.n = 34;
    for (int i = 0; i < 32; ++i) { s.xo[i] = OFF_C; s.yo[i] = AP(1 + i); s.oo[i] = OFF_CA + i * 16384; s.ao[i] = -1; }
    s.xo[32] = OFF_C;  s.yo[32] = OFF_B;  s.oo[32] = OFF_K;   s.ao[32] = OFF_D;
    s.xo[33] = AP(32); s.yo[33] = AP(32); s.oo[33] = OFF_A64; s.ao[33] = -1;
    hipLaunchKernelGGL(k_mmb, dim3(136), dim3(256), 0, stream, wsf, s);
    // S7: K[d] = CA[d]*B (d=1..31) ; W[j] = A^{31-j}*B (j=0..30) ; A96 ; A128
    s.n = 64;
    for (int i = 0; i < 31; ++i) { s.xo[i] = OFF_CA + i * 16384; s.yo[i] = OFF_B; s.oo[i] = OFF_K + (i + 1) * 16384; s.ao[i] = -1; }
    for (int j = 0; j < 31; ++j) { s.xo[31 + j] = AP(31 - j); s.yo[31 + j] = OFF_B; s.oo[31 + j] = OFF_W + j * 16384; s.ao[31 + j] = -1; }
    s.xo[62] = OFF_A64; s.yo[62] = AP(32);  s.oo[62] = OFF_A96;  s.ao[62] = -1;
    s.xo[63] = OFF_A64; s.yo[63] = OFF_A64; s.oo[63] = OFF_A128; s.ao[63] = -1;
    hipLaunchKernelGGL(k_mmb, dim3(256), dim3(256), 0, stream, wsf, s);

    hipLaunchKernelGGL(k_castmats, dim3(1616), dim3(256), 0, stream, wsf);
    hipLaunchKernelGGL(k_gemm1, dim3(BATCH), dim3(256), 0, stream, UBF, WBF, VBF);
    hipLaunchKernelGGL(k_comb2, dim3(BATCH), dim3(256), 0, stream, VBF, MCBF, SBF);
    hipLaunchKernelGGL(k_gemm3, dim3(512), dim3(256), 0, stream, UBF, SBF, KBF, CABF, out);
}

// Round 8
// 341.219 us; speedup vs baseline: 5.9760x; 1.1573x over previous
//
#include <hip/hip_runtime.h>
#include <cstddef>
#include <cstdint>

#define DIM 128
#define T_LEN 4096
#define BATCH 32
#define L_CH 32
#define N_CH 128
#define N_CHAINS 4096            // BATCH * N_CH
#define KFULL 4096               // L_CH * DIM

typedef float f32x4 __attribute__((ext_vector_type(4)));
typedef short s16x8 __attribute__((ext_vector_type(8)));
typedef unsigned short u16x4 __attribute__((ext_vector_type(4)));
typedef unsigned short u16x8 __attribute__((ext_vector_type(8)));
typedef unsigned int u32;

// ---- ws layout (float units) ----
#define OFF_UBF  0               // bf16 [4096][4096]       (8388608 f)
#define OFF_A64  8388608         // f32 A^64
#define OFF_A96  8404992         // f32 A^96
#define OFF_A128 8421376         // f32 A^128
#define OFF_VBF  8437760         // bf16 [32][136][128] (557056 u16 = 278528 f)
#define OFF_MCBF 8716288         // bf16 Mcat [128][640] (81920 u16 = 40960 f)
#define OFF_VP2  8757248         // f32 [4][4096][128] partials (2097152 f)
#define OFF_SBF  12582912        // bf16 [4096][128]
#define OFF_KBF  12845056        // bf16 K[0..31][128][128]
#define OFF_CABF 13107200        // bf16 CA[0..32][128][128] (slot0 unused)
#define OFF_WBF  13377536        // bf16 Wcat [128][4096]
#define OFF_AP   13639680        // f32 A^d slots d=0..32
#define OFF_CA   14180352        // f32 CA[1..32] at slot r-1
#define OFF_K    14704640        // f32 K[0..31]
#define OFF_W    15228928        // f32 W[0..31]
#define OFF_B    15753216        // f32 copies of B, C, D
#define OFF_C    15769600
#define OFF_D    15785984
#define AP(d)    (OFF_AP + (d) * 16384)

__device__ __forceinline__ f32x4 ld_pin(const float* p) {
    return *reinterpret_cast<const volatile f32x4*>(p);
}
__device__ __forceinline__ unsigned short f2bf(float x) {
    u32 u = __builtin_bit_cast(u32, x);
    return (unsigned short)((u + 0x7FFFu + ((u >> 16) & 1u)) >> 16);
}
__device__ __forceinline__ void gld16(const void* g, void* l) {
    __builtin_amdgcn_global_load_lds((const __attribute__((address_space(1))) u32*)g,
                                     (__attribute__((address_space(3))) u32*)l, 16, 0, 0);
}

// ---------------- fused: u fp32->bf16 cast  +  copy A,B,C,D into ws ----------------
__global__ void k_init(const float* __restrict__ u, const float* __restrict__ A,
                       const float* __restrict__ B, const float* __restrict__ C,
                       const float* __restrict__ D, float* __restrict__ wsf) {
    if (blockIdx.x < 8192) {
        unsigned short* ubf = (unsigned short*)(wsf + OFF_UBF);
        const size_t e0 = (size_t)(blockIdx.x * 256 + threadIdx.x) * 8;
        const f32x4 v0 = *reinterpret_cast<const f32x4*>(u + e0);
        const f32x4 v1 = *reinterpret_cast<const f32x4*>(u + e0 + 4);
        u16x8 o;
        o[0] = f2bf(v0.x); o[1] = f2bf(v0.y); o[2] = f2bf(v0.z); o[3] = f2bf(v0.w);
        o[4] = f2bf(v1.x); o[5] = f2bf(v1.y); o[6] = f2bf(v1.z); o[7] = f2bf(v1.w);
        *reinterpret_cast<u16x8*>(ubf + e0) = o;
    } else {
        const int e0 = ((blockIdx.x - 8192) * 256 + threadIdx.x) * 4;   // over 65536
        const int mat = e0 >> 14, rem = e0 & 16383;
        const float* src = (mat == 0) ? A : (mat == 1) ? B : (mat == 2) ? C : D;
        const int dst = (mat == 0) ? AP(1) : (mat == 1) ? OFF_B : (mat == 2) ? OFF_C : OFF_D;
        *reinterpret_cast<f32x4*>(wsf + dst + rem) =
            *reinterpret_cast<const f32x4*>(src + rem);
    }
}

// ---------------- castm2: Mcat (identity + A^32e) and W31 = B into WBF --------------
__global__ void k_castm2(float* __restrict__ wsf) {
    const int e0 = (blockIdx.x * 256 + threadIdx.x) * 4;   // over 98304
    unsigned short* MCBF = (unsigned short*)(wsf + OFF_MCBF);
    unsigned short* WBF  = (unsigned short*)(wsf + OFF_WBF);
    u16x4 o;
    unsigned short* dst;
    if (e0 < 81920) {                        // Mcat[i][e*128+k] = (A^32e)[i][k], e=0..4
        const int irow = e0 / 640;
        const int rem  = e0 - irow * 640;
        const int e    = rem >> 7;
        const int k    = rem & 127;
        if (e == 0) {
#pragma unroll
            for (int j = 0; j < 4; ++j)
                o[j] = (k + j == irow) ? (unsigned short)0x3F80 : (unsigned short)0;
        } else {
            const int moff = (e == 1) ? AP(32) : (e == 2) ? OFF_A64
                           : (e == 3) ? OFF_A96 : OFF_A128;
            const f32x4 v = *reinterpret_cast<const f32x4*>(wsf + moff + irow * 128 + k);
            o[0] = f2bf(v.x); o[1] = f2bf(v.y); o[2] = f2bf(v.z); o[3] = f2bf(v.w);
        }
        dst = MCBF + e0;
    } else {                                 // W31: Wcat[i][31*128+k] = B[i][k]
        const int widx = e0 - 81920;         // over 16384
        const int i = widx >> 7, k = widx & 127;
        const f32x4 v = *reinterpret_cast<const f32x4*>(wsf + OFF_B + i * 128 + k);
        o[0] = f2bf(v.x); o[1] = f2bf(v.y); o[2] = f2bf(v.z); o[3] = f2bf(v.w);
        dst = WBF + i * 4096 + 3968 + k;
    }
    *reinterpret_cast<u16x4*>(dst) = o;
}

// ------- batched 128x128 fp32 matmul: O = X*Y (+Add), optional bf16 dual-write ------
struct MMDesc { int n; int xo[64]; int yo[64]; int oo[64]; int ao[64]; int bo[64]; int bs[64]; };

__global__ __launch_bounds__(256, 1) void k_mmb(float* __restrict__ wsf, MMDesc d) {
    const int mm = blockIdx.x >> 2, sub = blockIdx.x & 3;
    const float* X = wsf + d.xo[mm];
    const float* Y = wsf + d.yo[mm];
    float* O = wsf + d.oo[mm];
    const int ao = d.ao[mm];
    __shared__ __align__(16) float Ys[DIM][DIM];
    const int t = threadIdx.x;
#pragma unroll
    for (int i = 0; i < 16; ++i) {
        const int j = t + i * 256;
        reinterpret_cast<f32x4*>(&Ys[0][0])[j] = reinterpret_cast<const f32x4*>(Y)[j];
    }
    const int r = sub * 32 + (t >> 3);
    const int c0 = (t & 7) * 16;
    f32x4 xr[32];
#pragma unroll
    for (int k = 0; k < 32; ++k) xr[k] = ld_pin(&X[r * DIM + 4 * k]);
    __syncthreads();
    float acc[16];
#pragma unroll
    for (int j = 0; j < 16; ++j) acc[j] = 0.f;
#pragma unroll
    for (int k = 0; k < DIM; ++k) {
        const float xv = ((const float*)xr)[k];
#pragma unroll
        for (int j = 0; j < 16; j += 4) {
            const f32x4 yv = *reinterpret_cast<const f32x4*>(&Ys[k][c0 + j]);
            acc[j + 0] = fmaf(xv, yv.x, acc[j + 0]);
            acc[j + 1] = fmaf(xv, yv.y, acc[j + 1]);
            acc[j + 2] = fmaf(xv, yv.z, acc[j + 2]);
            acc[j + 3] = fmaf(xv, yv.w, acc[j + 3]);
        }
    }
    if (ao >= 0) {
        const float* Ad = wsf + ao;
#pragma unroll
        for (int j = 0; j < 16; ++j) acc[j] += Ad[r * DIM + c0 + j];
    }
#pragma unroll
    for (int j = 0; j < 16; j += 4) {
        f32x4 o; o.x = acc[j]; o.y = acc[j + 1]; o.z = acc[j + 2]; o.w = acc[j + 3];
        *reinterpret_cast<f32x4*>(&O[r * DIM + c0 + j]) = o;
    }
    if (d.bo[mm] >= 0) {                      // bf16 dual-write
        unsigned short* bw = (unsigned short*)wsf + (size_t)d.bo[mm] + (size_t)r * d.bs[mm] + c0;
#pragma unroll
        for (int j = 0; j < 16; j += 4) {
            u16x4 ob;
            ob[0] = f2bf(acc[j]); ob[1] = f2bf(acc[j + 1]);
            ob[2] = f2bf(acc[j + 2]); ob[3] = f2bf(acc[j + 3]);
            *reinterpret_cast<u16x4*>(bw + j) = ob;
        }
    }
}

// ---- GEMM1 (K-split x4): VP2[ksp][m][i] = sum_{k in split} Ubf[m][k] * Wcat[i][k] --
__global__ __launch_bounds__(256, 2) void k_gemm1(const unsigned short* __restrict__ UBF,
                                                  const unsigned short* __restrict__ WBF,
                                                  float* __restrict__ VP) {
    __shared__ __align__(16) unsigned short lsA[2][4096];
    __shared__ __align__(16) unsigned short lsB[2][4096];
    const int b = blockIdx.x >> 2, ksp = blockIdx.x & 3;
    const int t = threadIdx.x, w = t >> 6, l = t & 63;
    const int wr = w >> 1, wc = w & 1;
    const int m0 = b * 128;
    const int rowA0 = w * 32 + (l >> 2);
    const int scol8 = ((l & 3) ^ ((l >> 3) & 3)) * 8;   // swizzled source chunk
    const int rsw   = ((l >> 4) ^ ((l >> 1) & 3)) * 8;  // swizzled read chunk
    const int wvb = w * 1024;
    const int kb = ksp * 1024;

    f32x4 acc[4][4];
#pragma unroll
    for (int a = 0; a < 4; ++a)
#pragma unroll
        for (int c = 0; c < 4; ++c) acc[a][c] = (f32x4)(0.f);

#define STAGE1(q, buf) do {                                                        \
    const int kq = kb + (q) * 32 + scol8;                                          \
    const unsigned short* ga = UBF + (size_t)(m0 + rowA0) * KFULL + kq;            \
    const unsigned short* gb = WBF + (size_t)rowA0 * KFULL + kq;                   \
    gld16(ga, &lsA[buf][wvb]);  gld16(ga + 16 * KFULL, &lsA[buf][wvb + 512]);      \
    gld16(gb, &lsB[buf][wvb]);  gld16(gb + 16 * KFULL, &lsB[buf][wvb + 512]);      \
} while (0)

    STAGE1(0, 0);
    __syncthreads();
#pragma unroll 1
    for (int q = 0; q < 32; ++q) {
        const int buf = q & 1;
        if (q + 1 < 32) STAGE1(q + 1, buf ^ 1);
        s16x8 af[4], bfr[4];
#pragma unroll
        for (int mi = 0; mi < 4; ++mi)
            af[mi] = *(const s16x8*)(&lsA[buf][(wr * 64 + mi * 16 + (l & 15)) * 32 + rsw]);
#pragma unroll
        for (int ni = 0; ni < 4; ++ni)
            bfr[ni] = *(const s16x8*)(&lsB[buf][(wc * 64 + ni * 16 + (l & 15)) * 32 + rsw]);
#pragma unroll
        for (int mi = 0; mi < 4; ++mi)
#pragma unroll
            for (int ni = 0; ni < 4; ++ni)
                acc[mi][ni] = __builtin_amdgcn_mfma_f32_16x16x32_bf16(af[mi], bfr[ni], acc[mi][ni], 0, 0, 0);
        __syncthreads();
    }
    float* vp = VP + (size_t)ksp * (N_CHAINS * DIM);
    const int row0 = wr * 64 + (l >> 4) * 4;
    const int col0 = wc * 64 + (l & 15);
#pragma unroll
    for (int mi = 0; mi < 4; ++mi)
#pragma unroll
        for (int ni = 0; ni < 4; ++ni)
#pragma unroll
            for (int jj = 0; jj < 4; ++jj)
                vp[(size_t)(m0 + row0 + mi * 16 + jj) * DIM + col0 + ni * 16] = acc[mi][ni][jj];
#undef STAGE1
}

// ---------------- vred: V = sum of 4 partials -> bf16 VBF (+ zero pad rows) ---------
__global__ void k_vred(const float* __restrict__ VP, unsigned short* __restrict__ VBF) {
    if (blockIdx.x < 512) {
        const int g = (blockIdx.x * 256 + threadIdx.x) * 4;   // over 524288
        f32x4 s = *reinterpret_cast<const f32x4*>(VP + g);
#pragma unroll
        for (int sp = 1; sp < 4; ++sp) {
            const f32x4 v = *reinterpret_cast<const f32x4*>(VP + sp * 524288 + g);
            s.x += v.x; s.y += v.y; s.z += v.z; s.w += v.w;
        }
        const int m = g >> 7, i = g & 127;
        const int b = m >> 7, c = m & 127;
        u16x4 o;
        o[0] = f2bf(s.x); o[1] = f2bf(s.y); o[2] = f2bf(s.z); o[3] = f2bf(s.w);
        *reinterpret_cast<u16x4*>(VBF + b * 17408 + (8 + c) * 128 + i) = o;
    } else {
        const int z = ((blockIdx.x - 512) * 256 + threadIdx.x) * 4;   // over 32768
        const int b = z >> 10, rem = z & 1023;
        u16x4 zz; zz[0] = 0; zz[1] = 0; zz[2] = 0; zz[3] = 0;
        *reinterpret_cast<u16x4*>(VBF + b * 17408 + rem) = zz;
    }
}

// ---------------- comb2: S[b][c] = sum_{e=0..4} (A^32)^e V[b][c-1-e]  (banded) ------
__global__ __launch_bounds__(256, 2) void k_comb2(const unsigned short* __restrict__ VBF,
                                                  const unsigned short* __restrict__ MCBF,
                                                  unsigned short* __restrict__ SBF) {
    __shared__ __align__(16) unsigned short lsA[2][4096];
    __shared__ __align__(16) unsigned short lsB[2][4096];
    const int b = blockIdx.x;
    const int t = threadIdx.x, w = t >> 6, l = t & 63;
    const int wr = w >> 1, wc = w & 1;
    const int rowA0 = w * 32 + (l >> 2);
    const int scol8 = ((l & 3) ^ ((l >> 3) & 3)) * 8;
    const int rsw   = ((l >> 4) ^ ((l >> 1) & 3)) * 8;
    const int wvb = w * 1024;
    const unsigned short* Vb = VBF + b * 17408;

    f32x4 acc[4][4];
#pragma unroll
    for (int a = 0; a < 4; ++a)
#pragma unroll
        for (int c = 0; c < 4; ++c) acc[a][c] = (f32x4)(0.f);

#define STAGEC(q, buf) do {                                                        \
    const int kq = (q) * 32 + scol8;                                               \
    const int e = kq >> 7, kk = kq & 127;                                          \
    const unsigned short* ga = Vb + (8 + rowA0 - 1 - e) * 128 + kk;                \
    const unsigned short* gb = MCBF + rowA0 * 640 + kq;                            \
    gld16(ga, &lsA[buf][wvb]);  gld16(ga + 16 * 128, &lsA[buf][wvb + 512]);        \
    gld16(gb, &lsB[buf][wvb]);  gld16(gb + 16 * 640, &lsB[buf][wvb + 512]);        \
} while (0)

    STAGEC(0, 0);
    __syncthreads();
#pragma unroll 1
    for (int q = 0; q < 20; ++q) {
        const int buf = q & 1;
        if (q + 1 < 20) STAGEC(q + 1, buf ^ 1);
        s16x8 af[4], bfr[4];
#pragma unroll
        for (int mi = 0; mi < 4; ++mi)
            af[mi] = *(const s16x8*)(&lsA[buf][(wr * 64 + mi * 16 + (l & 15)) * 32 + rsw]);
#pragma unroll
        for (int ni = 0; ni < 4; ++ni)
            bfr[ni] = *(const s16x8*)(&lsB[buf][(wc * 64 + ni * 16 + (l & 15)) * 32 + rsw]);
#pragma unroll
        for (int mi = 0; mi < 4; ++mi)
#pragma unroll
            for (int ni = 0; ni < 4; ++ni)
                acc[mi][ni] = __builtin_amdgcn_mfma_f32_16x16x32_bf16(af[mi], bfr[ni], acc[mi][ni], 0, 0, 0);
        __syncthreads();
    }
    const int row0 = wr * 64 + (l >> 4) * 4;
    const int col0 = wc * 64 + (l & 15);
#pragma unroll
    for (int mi = 0; mi < 4; ++mi)
#pragma unroll
        for (int ni = 0; ni < 4; ++ni)
#pragma unroll
            for (int jj = 0; jj < 4; ++jj)
                SBF[(size_t)(b * 128 + row0 + mi * 16 + jj) * 128 + col0 + ni * 16] =
                    f2bf(acc[mi][ni][jj]);
#undef STAGEC
}

// ---------------- GEMM3: y tile (bm, r) = sum_{j<=r} U_j K_{r-j}^T + S CA[r+1]^T ----
// 1024 blocks, r descending so heavy tiles dispatch first
__global__ __launch_bounds__(256, 2) void k_gemm3(const unsigned short* __restrict__ UBF,
                                                  const unsigned short* __restrict__ SBF,
                                                  const unsigned short* __restrict__ KBF,
                                                  const unsigned short* __restrict__ CABF,
                                                  float* __restrict__ out) {
    __shared__ __align__(16) unsigned short lsA[2][4096];
    __shared__ __align__(16) unsigned short lsB[2][4096];
    const int r = 31 - (blockIdx.x >> 5);
    const int bm = blockIdx.x & 31;
    const int t = threadIdx.x, w = t >> 6, l = t & 63;
    const int wr = w >> 1, wc = w & 1;
    const int m0 = bm * 128;
    const int rowA0 = w * 32 + (l >> 2);
    const int scol8 = ((l & 3) ^ ((l >> 3) & 3)) * 8;
    const int rsw   = ((l >> 4) ^ ((l >> 1) & 3)) * 8;
    const int wvb = w * 1024;
    const int NS = 4 * r + 8;

    f32x4 acc[4][4];
#pragma unroll
    for (int a = 0; a < 4; ++a)
#pragma unroll
        for (int c = 0; c < 4; ++c) acc[a][c] = (f32x4)(0.f);

#define STAGE3(q, buf) do {                                                            \
    const unsigned short *ga, *gb;  int strA, strB;                                    \
    if ((q) < 4 * (r + 1)) {                                                           \
        ga = UBF + (size_t)(m0 + rowA0) * KFULL + (q) * 32 + scol8;  strA = KFULL;     \
        gb = KBF + (size_t)(r - ((q) >> 2)) * 16384 + rowA0 * 128                      \
             + ((q) & 3) * 32 + scol8;                               strB = 128;       \
    } else {                                                                           \
        ga = SBF + (size_t)(m0 + rowA0) * 128 + ((q) & 3) * 32 + scol8;  strA = 128;   \
        gb = CABF + (size_t)(r + 1) * 16384 + rowA0 * 128 + ((q) & 3) * 32 + scol8;    \
        strB = 128;                                                                    \
    }                                                                                  \
    gld16(ga, &lsA[buf][wvb]);  gld16(ga + 16 * strA, &lsA[buf][wvb + 512]);           \
    gld16(gb, &lsB[buf][wvb]);  gld16(gb + 16 * strB, &lsB[buf][wvb + 512]);           \
} while (0)

    STAGE3(0, 0);
    __syncthreads();
#pragma unroll 1
    for (int q = 0; q < NS; ++q) {
        const int buf = q & 1;
        if (q + 1 < NS) STAGE3(q + 1, buf ^ 1);
        s16x8 af[4], bfr[4];
#pragma unroll
        for (int mi = 0; mi < 4; ++mi)
            af[mi] = *(const s16x8*)(&lsA[buf][(wr * 64 + mi * 16 + (l & 15)) * 32 + rsw]);
#pragma unroll
        for (int ni = 0; ni < 4; ++ni)
            bfr[ni] = *(const s16x8*)(&lsB[buf][(wc * 64 + ni * 16 + (l & 15)) * 32 + rsw]);
#pragma unroll
        for (int mi = 0; mi < 4; ++mi)
#pragma unroll
            for (int ni = 0; ni < 4; ++ni)
                acc[mi][ni] = __builtin_amdgcn_mfma_f32_16x16x32_bf16(af[mi], bfr[ni], acc[mi][ni], 0, 0, 0);
        __syncthreads();
    }
    const int row0 = wr * 64 + (l >> 4) * 4;
    const int col0 = wc * 64 + (l & 15);
#pragma unroll
    for (int mi = 0; mi < 4; ++mi)
#pragma unroll
        for (int ni = 0; ni < 4; ++ni)
#pragma unroll
            for (int jj = 0; jj < 4; ++jj)
                out[(size_t)(m0 + row0 + mi * 16 + jj) * KFULL + r * 128 + col0 + ni * 16] =
                    acc[mi][ni][jj];
#undef STAGE3
}

extern "C" void kernel_launch(void* const* d_in, const int* in_sizes, int n_in,
                              void* d_out, int out_size, void* d_ws, size_t ws_size,
                              hipStream_t stream) {
    const float* u  = (const float*)d_in[0];
    const float* Am = (const float*)d_in[1];
    const float* Bm = (const float*)d_in[2];
    const float* Cm = (const float*)d_in[3];
    const float* Dm = (const float*)d_in[4];
    float* out = (float*)d_out;
    float* wsf = (float*)d_ws;

    unsigned short* UBF  = (unsigned short*)(wsf + OFF_UBF);
    unsigned short* SBF  = (unsigned short*)(wsf + OFF_SBF);
    unsigned short* KBF  = (unsigned short*)(wsf + OFF_KBF);
    unsigned short* CABF = (unsigned short*)(wsf + OFF_CABF);
    unsigned short* WBF  = (unsigned short*)(wsf + OFF_WBF);
    unsigned short* VBF  = (unsigned short*)(wsf + OFF_VBF);
    unsigned short* MCBF = (unsigned short*)(wsf + OFF_MCBF);
    float* VP2 = wsf + OFF_VP2;

    const int KBF_U  = 2 * OFF_KBF;
    const int CABF_U = 2 * OFF_CABF;
    const int WBF_U  = 2 * OFF_WBF;

    hipLaunchKernelGGL(k_init, dim3(8256), dim3(256), 0, stream, u, Am, Bm, Cm, Dm, wsf);

    // power / product stages
    MMDesc s;
    for (int i = 0; i < 64; ++i) { s.bo[i] = -1; s.bs[i] = 0; }
    // S1: A2 = A*A
    s.n = 1; s.xo[0] = AP(1); s.yo[0] = AP(1); s.oo[0] = AP(2); s.ao[0] = -1;
    hipLaunchKernelGGL(k_mmb, dim3(4), dim3(256), 0, stream, wsf, s);
    // S2: A3 = A2*A ; A4 = A2*A2
    s.n = 2;
    s.xo[0] = AP(2); s.yo[0] = AP(1); s.oo[0] = AP(3); s.ao[0] = -1;
    s.xo[1] = AP(2); s.yo[1] = AP(2); s.oo[1] = AP(4); s.ao[1] = -1;
    hipLaunchKernelGGL(k_mmb, dim3(8), dim3(256), 0, stream, wsf, s);
    // S3: A5..A8 = A4*A1..A4
    s.n = 4;
    for (int i = 0; i < 4; ++i) { s.xo[i] = AP(4); s.yo[i] = AP(1 + i); s.oo[i] = AP(5 + i); s.ao[i] = -1; }
    hipLaunchKernelGGL(k_mmb, dim3(16), dim3(256), 0, stream, wsf, s);
    // S4: A9..A16 = A8*A1..A8
    s.n = 8;
    for (int i = 0; i < 8; ++i) { s.xo[i] = AP(8); s.yo[i] = AP(1 + i); s.oo[i] = AP(9 + i); s.ao[i] = -1; }
    hipLaunchKernelGGL(k_mmb, dim3(32), dim3(256), 0, stream, wsf, s);
    // S5: A17..A32 = A16*A1..A16
    s.n = 16;
    for (int i = 0; i < 16; ++i) { s.xo[i] = AP(16); s.yo[i] = AP(1 + i); s.oo[i] = AP(17 + i); s.ao[i] = -1; }
    hipLaunchKernelGGL(k_mmb, dim3(64), dim3(256), 0, stream, wsf, s);
    // S6: CA[d] = C*A^d (d=1..32, dual->CABF) ; K0 = C*B + D (dual->KBF) ; A64
    s.n = 34;
    for (int i = 0; i < 32; ++i) {
        s.xo[i] = OFF_C; s.yo[i] = AP(1 + i); s.oo[i] = OFF_CA + i * 16384; s.ao[i] = -1;
        s.bo[i] = CABF_U + (i + 1) * 16384; s.bs[i] = 128;
    }
    s.xo[32] = OFF_C;  s.yo[32] = OFF_B;  s.oo[32] = OFF_K;   s.ao[32] = OFF_D;
    s.bo[32] = KBF_U;  s.bs[32] = 128;
    s.xo[33] = AP(32); s.yo[33] = AP(32); s.oo[33] = OFF_A64; s.ao[33] = -1; s.bo[33] = -1;
    hipLaunchKernelGGL(k_mmb, dim3(136), dim3(256), 0, stream, wsf, s);
    // S7: K[d]=CA[d]*B (dual->KBF) ; W[j]=A^{31-j}*B (dual->WBF col-block) ; A96 ; A128
    s.n = 64;
    for (int i = 0; i < 31; ++i) {
        s.xo[i] = OFF_CA + i * 16384; s.yo[i] = OFF_B; s.oo[i] = OFF_K + (i + 1) * 16384; s.ao[i] = -1;
        s.bo[i] = KBF_U + (i + 1) * 16384; s.bs[i] = 128;
    }
    for (int j = 0; j < 31; ++j) {
        s.xo[31 + j] = AP(31 - j); s.yo[31 + j] = OFF_B; s.oo[31 + j] = OFF_W + j * 16384; s.ao[31 + j] = -1;
        s.bo[31 + j] = WBF_U + j * 128; s.bs[31 + j] = 4096;
    }
    s.xo[62] = OFF_A64; s.yo[62] = AP(32);  s.oo[62] = OFF_A96;  s.ao[62] = -1; s.bo[62] = -1;
    s.xo[63] = OFF_A64; s.yo[63] = OFF_A64; s.oo[63] = OFF_A128; s.ao[63] = -1; s.bo[63] = -1;
    hipLaunchKernelGGL(k_mmb, dim3(256), dim3(256), 0, stream, wsf, s);

    hipLaunchKernelGGL(k_castm2, dim3(96), dim3(256), 0, stream, wsf);
    hipLaunchKernelGGL(k_gemm1, dim3(128), dim3(256), 0, stream, UBF, WBF, VP2);
    hipLaunchKernelGGL(k_vred, dim3(544), dim3(256), 0, stream, VP2, VBF);
    hipLaunchKernelGGL(k_comb2, dim3(BATCH), dim3(256), 0, stream, VBF, MCBF, SBF);
    hipLaunchKernelGGL(k_gemm3, dim3(1024), dim3(256), 0, stream, UBF, SBF, KBF, CABF, out);
}

// Round 11
// 328.419 us; speedup vs baseline: 6.2089x; 1.0390x over previous
//
#include <hip/hip_runtime.h>
#include <cstddef>
#include <cstdint>

#define DIM 128
#define T_LEN 4096
#define BATCH 32
#define L_CH 32
#define N_CH 128
#define N_CHAINS 4096            // BATCH * N_CH
#define KFULL 4096               // L_CH * DIM

typedef float f32x4 __attribute__((ext_vector_type(4)));
typedef short s16x8 __attribute__((ext_vector_type(8)));
typedef unsigned short u16x4 __attribute__((ext_vector_type(4)));
typedef unsigned short u16x8 __attribute__((ext_vector_type(8)));
typedef unsigned int u32;

// ---- ws layout (float units) ----
#define OFF_UBF  0               // bf16 [4096][4096]       (8388608 f)
#define OFF_A64  8388608         // f32 A^64
#define OFF_VBF  8437760         // bf16 [32][136][128] (557056 u16 = 278528 f)
#define OFF_MCBF 8716288         // bf16 Mcat [128][384] (49152 u16 = 24576 f)
#define OFF_VP2  8757248         // f32 [4][4096][128] partials (2097152 f)
#define OFF_SBF  12582912        // bf16 [4096][128]
#define OFF_KBF  12845056        // bf16 K[0..31][128][128]
#define OFF_CABF 13107200        // bf16 CA[0..32][128][128] (slot0 unused)
#define OFF_WBF  13377536        // bf16 Wcat [128][4096]  (Wcat[i][j*128+k]=E[31-j][i][k])
#define OFF_AP   13639680        // f32 A^d slots d=0..32
#define OFF_CA   14180352        // f32 CA[1..32] at slot d-1
#define OFF_K    14704640        // f32 K[0..31]
#define OFF_W    15228928        // f32 E[0..31] (E[e]=A^e B; E[0]=B not stored here)
#define OFF_B    15753216        // f32 copies of B, C, D
#define OFF_C    15769600
#define OFF_D    15785984
#define AP(d)    (OFF_AP + (d) * 16384)

#define KBF_U  (2 * OFF_KBF)
#define CABF_U (2 * OFF_CABF)
#define WBF_U  (2 * OFF_WBF)

__device__ __forceinline__ f32x4 ld_pin(const float* p) {
    return *reinterpret_cast<const volatile f32x4*>(p);
}
__device__ __forceinline__ unsigned short f2bf(float x) {
    u32 u = __builtin_bit_cast(u32, x);
    return (unsigned short)((u + 0x7FFFu + ((u >> 16) & 1u)) >> 16);
}
__device__ __forceinline__ void gld16(const void* g, void* l) {
    __builtin_amdgcn_global_load_lds((const __attribute__((address_space(1))) u32*)g,
                                     (__attribute__((address_space(3))) u32*)l, 16, 0, 0);
}

// ---------------- fused: u fp32->bf16 cast  +  copy A,B,C,D into ws ----------------
__global__ void k_init(const float* __restrict__ u, const float* __restrict__ A,
                       const float* __restrict__ B, const float* __restrict__ C,
                       const float* __restrict__ D, float* __restrict__ wsf) {
    if (blockIdx.x < 8192) {
        unsigned short* ubf = (unsigned short*)(wsf + OFF_UBF);
        const size_t e0 = (size_t)(blockIdx.x * 256 + threadIdx.x) * 8;
        const f32x4 v0 = *reinterpret_cast<const f32x4*>(u + e0);
        const f32x4 v1 = *reinterpret_cast<const f32x4*>(u + e0 + 4);
        u16x8 o;
        o[0] = f2bf(v0.x); o[1] = f2bf(v0.y); o[2] = f2bf(v0.z); o[3] = f2bf(v0.w);
        o[4] = f2bf(v1.x); o[5] = f2bf(v1.y); o[6] = f2bf(v1.z); o[7] = f2bf(v1.w);
        *reinterpret_cast<u16x8*>(ubf + e0) = o;
    } else {
        const int e0 = ((blockIdx.x - 8192) * 256 + threadIdx.x) * 4;   // over 65536
        const int mat = e0 >> 14, rem = e0 & 16383;
        const float* src = (mat == 0) ? A : (mat == 1) ? B : (mat == 2) ? C : D;
        const int dst = (mat == 0) ? AP(1) : (mat == 1) ? OFF_B : (mat == 2) ? OFF_C : OFF_D;
        *reinterpret_cast<f32x4*>(wsf + dst + rem) =
            *reinterpret_cast<const f32x4*>(src + rem);
    }
}

// ---------------- castm2: Mcat (I, A32, A64) and W31 = B into WBF -------------------
__global__ void k_castm2(float* __restrict__ wsf) {
    const int e0 = (blockIdx.x * 256 + threadIdx.x) * 4;   // over 65536
    unsigned short* MCBF = (unsigned short*)(wsf + OFF_MCBF);
    unsigned short* WBF  = (unsigned short*)(wsf + OFF_WBF);
    u16x4 o;
    unsigned short* dst;
    if (e0 < 49152) {                        // Mcat[i][e*128+k] = (A^32e)[i][k], e=0..2
        const int irow = e0 / 384;
        const int rem  = e0 - irow * 384;
        const int e    = rem >> 7;
        const int k    = rem & 127;
        if (e == 0) {
#pragma unroll
            for (int j = 0; j < 4; ++j)
                o[j] = (k + j == irow) ? (unsigned short)0x3F80 : (unsigned short)0;
        } else {
            const int moff = (e == 1) ? AP(32) : OFF_A64;
            const f32x4 v = *reinterpret_cast<const f32x4*>(wsf + moff + irow * 128 + k);
            o[0] = f2bf(v.x); o[1] = f2bf(v.y); o[2] = f2bf(v.z); o[3] = f2bf(v.w);
        }
        dst = MCBF + e0;
    } else {                                 // W31: Wcat[i][31*128+k] = B[i][k]
        const int widx = e0 - 49152;         // over 16384
        const int i = widx >> 7, k = widx & 127;
        const f32x4 v = *reinterpret_cast<const f32x4*>(wsf + OFF_B + i * 128 + k);
        o[0] = f2bf(v.x); o[1] = f2bf(v.y); o[2] = f2bf(v.z); o[3] = f2bf(v.w);
        dst = WBF + i * 4096 + 3968 + k;
    }
    *reinterpret_cast<u16x4*>(dst) = o;
}

// ------- batched 128x128 fp32 matmul: O = X*Y (+Add), optional bf16 dual-write ------
struct MMDesc { int n; int xo[64]; int yo[64]; int oo[64]; int ao[64]; int bo[64]; int bs[64]; };

__global__ __launch_bounds__(256, 1) void k_mmb(float* __restrict__ wsf, MMDesc d) {
    const int mm = blockIdx.x >> 2, sub = blockIdx.x & 3;
    const float* X = wsf + d.xo[mm];
    const float* Y = wsf + d.yo[mm];
    float* O = wsf + d.oo[mm];
    const int ao = d.ao[mm];
    __shared__ __align__(16) float Ys[DIM][DIM];
    const int t = threadIdx.x;
#pragma unroll
    for (int i = 0; i < 16; ++i) {
        const int j = t + i * 256;
        reinterpret_cast<f32x4*>(&Ys[0][0])[j] = reinterpret_cast<const f32x4*>(Y)[j];
    }
    const int r = sub * 32 + (t >> 3);
    const int c0 = (t & 7) * 16;
    f32x4 xr[32];
#pragma unroll
    for (int k = 0; k < 32; ++k) xr[k] = ld_pin(&X[r * DIM + 4 * k]);
    __syncthreads();
    float acc[16];
#pragma unroll
    for (int j = 0; j < 16; ++j) acc[j] = 0.f;
#pragma unroll
    for (int k = 0; k < DIM; ++k) {
        const float xv = ((const float*)xr)[k];
#pragma unroll
        for (int j = 0; j < 16; j += 4) {
            const f32x4 yv = *reinterpret_cast<const f32x4*>(&Ys[k][c0 + j]);
            acc[j + 0] = fmaf(xv, yv.x, acc[j + 0]);
            acc[j + 1] = fmaf(xv, yv.y, acc[j + 1]);
            acc[j + 2] = fmaf(xv, yv.z, acc[j + 2]);
            acc[j + 3] = fmaf(xv, yv.w, acc[j + 3]);
        }
    }
    if (ao >= 0) {
        const float* Ad = wsf + ao;
#pragma unroll
        for (int j = 0; j < 16; ++j) acc[j] += Ad[r * DIM + c0 + j];
    }
#pragma unroll
    for (int j = 0; j < 16; j += 4) {
        f32x4 o; o.x = acc[j]; o.y = acc[j + 1]; o.z = acc[j + 2]; o.w = acc[j + 3];
        *reinterpret_cast<f32x4*>(&O[r * DIM + c0 + j]) = o;
    }
    if (d.bo[mm] >= 0) {                      // bf16 dual-write
        unsigned short* bw = (unsigned short*)wsf + (size_t)d.bo[mm] + (size_t)r * d.bs[mm] + c0;
#pragma unroll
        for (int j = 0; j < 16; j += 4) {
            u16x4 ob;
            ob[0] = f2bf(acc[j]); ob[1] = f2bf(acc[j + 1]);
            ob[2] = f2bf(acc[j + 2]); ob[3] = f2bf(acc[j + 3]);
            *reinterpret_cast<u16x4*>(bw + j) = ob;
        }
    }
}

// ---- GEMM1 (K-split x4): VP2[ksp][m][i] = sum_{k in split} Ubf[m][k] * Wcat[i][k] --
__global__ __launch_bounds__(256, 2) void k_gemm1(const unsigned short* __restrict__ UBF,
                                                  const unsigned short* __restrict__ WBF,
                                                  float* __restrict__ VP) {
    __shared__ __align__(16) unsigned short lsA[2][4096];
    __shared__ __align__(16) unsigned short lsB[2][4096];
    const int b = blockIdx.x >> 2, ksp = blockIdx.x & 3;
    const int t = threadIdx.x, w = t >> 6, l = t & 63;
    const int wr = w >> 1, wc = w & 1;
    const int m0 = b * 128;
    const int rowA0 = w * 32 + (l >> 2);
    const int scol8 = ((l & 3) ^ ((l >> 3) & 3)) * 8;   // swizzled source chunk
    const int rsw   = ((l >> 4) ^ ((l >> 1) & 3)) * 8;  // swizzled read chunk
    const int wvb = w * 1024;
    const int kb = ksp * 1024;

    f32x4 acc[4][4];
#pragma unroll
    for (int a = 0; a < 4; ++a)
#pragma unroll
        for (int c = 0; c < 4; ++c) acc[a][c] = (f32x4)(0.f);

#define STAGE1(q, buf) do {                                                        \
    const int kq = kb + (q) * 32 + scol8;                                          \
    const unsigned short* ga = UBF + (size_t)(m0 + rowA0) * KFULL + kq;            \
    const unsigned short* gb = WBF + (size_t)rowA0 * KFULL + kq;                   \
    gld16(ga, &lsA[buf][wvb]);  gld16(ga + 16 * KFULL, &lsA[buf][wvb + 512]);      \
    gld16(gb, &lsB[buf][wvb]);  gld16(gb + 16 * KFULL, &lsB[buf][wvb + 512]);      \
} while (0)

    STAGE1(0, 0);
    __syncthreads();
#pragma unroll 1
    for (int q = 0; q < 32; ++q) {
        const int buf = q & 1;
        if (q + 1 < 32) STAGE1(q + 1, buf ^ 1);
        s16x8 af[4], bfr[4];
#pragma unroll
        for (int mi = 0; mi < 4; ++mi)
            af[mi] = *(const s16x8*)(&lsA[buf][(wr * 64 + mi * 16 + (l & 15)) * 32 + rsw]);
#pragma unroll
        for (int ni = 0; ni < 4; ++ni)
            bfr[ni] = *(const s16x8*)(&lsB[buf][(wc * 64 + ni * 16 + (l & 15)) * 32 + rsw]);
#pragma unroll
        for (int mi = 0; mi < 4; ++mi)
#pragma unroll
            for (int ni = 0; ni < 4; ++ni)
                acc[mi][ni] = __builtin_amdgcn_mfma_f32_16x16x32_bf16(af[mi], bfr[ni], acc[mi][ni], 0, 0, 0);
        __syncthreads();
    }
    float* vp = VP + (size_t)ksp * (N_CHAINS * DIM);
    const int row0 = wr * 64 + (l >> 4) * 4;
    const int col0 = wc * 64 + (l & 15);
#pragma unroll
    for (int mi = 0; mi < 4; ++mi)
#pragma unroll
        for (int ni = 0; ni < 4; ++ni)
#pragma unroll
            for (int jj = 0; jj < 4; ++jj)
                vp[(size_t)(m0 + row0 + mi * 16 + jj) * DIM + col0 + ni * 16] = acc[mi][ni][jj];
#undef STAGE1
}

// ---- comb2 (fused vred): reduce partials -> bf16 V, then banded boundary GEMM -----
// S[b][c] = sum_{e=0..2} (A^32)^e V[b][c-1-e]   (truncation err ~0.9^96 = 4e-5)
__global__ __launch_bounds__(256, 2) void k_comb2(const float* __restrict__ VP,
                                                  const unsigned short* __restrict__ MCBF,
                                                  unsigned short* __restrict__ VBF,
                                                  unsigned short* __restrict__ SBF) {
    __shared__ __align__(16) unsigned short lsA[2][4096];
    __shared__ __align__(16) unsigned short lsB[2][4096];
    const int b = blockIdx.x;
    const int t = threadIdx.x, w = t >> 6, l = t & 63;
    const int wr = w >> 1, wc = w & 1;
    const int rowA0 = w * 32 + (l >> 2);
    const int scol8 = ((l & 3) ^ ((l >> 3) & 3)) * 8;
    const int rsw   = ((l >> 4) ^ ((l >> 1) & 3)) * 8;
    const int wvb = w * 1024;
    unsigned short* Vb = VBF + b * 17408;

    // phase 0: V = sum of 4 partials -> bf16 (+ zero pad rows 0..7)
    {
        u16x4 z; z[0] = 0; z[1] = 0; z[2] = 0; z[3] = 0;
        *reinterpret_cast<u16x4*>(Vb + t * 4) = z;            // 1024 pad elems
        const int base = b * 16384;
#pragma unroll
        for (int it = 0; it < 16; ++it) {
            const int local = (it * 256 + t) * 4;
            const int g = base + local;
            f32x4 s = *reinterpret_cast<const f32x4*>(VP + g);
#pragma unroll
            for (int sp = 1; sp < 4; ++sp) {
                const f32x4 v = *reinterpret_cast<const f32x4*>(VP + sp * 524288 + g);
                s.x += v.x; s.y += v.y; s.z += v.z; s.w += v.w;
            }
            u16x4 o;
            o[0] = f2bf(s.x); o[1] = f2bf(s.y); o[2] = f2bf(s.z); o[3] = f2bf(s.w);
            *reinterpret_cast<u16x4*>(Vb + 1024 + local) = o;
        }
    }
    __syncthreads();   // drains vmcnt: V writes visible to this block's loads

    f32x4 acc[4][4];
#pragma unroll
    for (int a = 0; a < 4; ++a)
#pragma unroll
        for (int c = 0; c < 4; ++c) acc[a][c] = (f32x4)(0.f);

#define STAGEC(q, buf) do {                                                        \
    const int kq = (q) * 32 + scol8;                                               \
    const int e = kq >> 7, kk = kq & 127;                                          \
    const unsigned short* ga = Vb + (8 + rowA0 - 1 - e) * 128 + kk;                \
    const unsigned short* gb = MCBF + rowA0 * 384 + kq;                            \
    gld16(ga, &lsA[buf][wvb]);  gld16(ga + 16 * 128, &lsA[buf][wvb + 512]);        \
    gld16(gb, &lsB[buf][wvb]);  gld16(gb + 16 * 384, &lsB[buf][wvb + 512]);        \
} while (0)

    STAGEC(0, 0);
    __syncthreads();
#pragma unroll 1
    for (int q = 0; q < 12; ++q) {
        const int buf = q & 1;
        if (q + 1 < 12) STAGEC(q + 1, buf ^ 1);
        s16x8 af[4], bfr[4];
#pragma unroll
        for (int mi = 0; mi < 4; ++mi)
            af[mi] = *(const s16x8*)(&lsA[buf][(wr * 64 + mi * 16 + (l & 15)) * 32 + rsw]);
#pragma unroll
        for (int ni = 0; ni < 4; ++ni)
            bfr[ni] = *(const s16x8*)(&lsB[buf][(wc * 64 + ni * 16 + (l & 15)) * 32 + rsw]);
#pragma unroll
        for (int mi = 0; mi < 4; ++mi)
#pragma unroll
            for (int ni = 0; ni < 4; ++ni)
                acc[mi][ni] = __builtin_amdgcn_mfma_f32_16x16x32_bf16(af[mi], bfr[ni], acc[mi][ni], 0, 0, 0);
        __syncthreads();
    }
    const int row0 = wr * 64 + (l >> 4) * 4;
    const int col0 = wc * 64 + (l & 15);
#pragma unroll
    for (int mi = 0; mi < 4; ++mi)
#pragma unroll
        for (int ni = 0; ni < 4; ++ni)
#pragma unroll
            for (int jj = 0; jj < 4; ++jj)
                SBF[(size_t)(b * 128 + row0 + mi * 16 + jj) * 128 + col0 + ni * 16] =
                    f2bf(acc[mi][ni][jj]);
#undef STAGEC
}

// ---------------- GEMM3: y tile (bm, r) = sum_{j<=r} U_j K_{r-j}^T + S CA[r+1]^T ----
// 1024 blocks, r descending so heavy tiles dispatch first
__global__ __launch_bounds__(256, 2) void k_gemm3(const unsigned short* __restrict__ UBF,
                                                  const unsigned short* __restrict__ SBF,
                                                  const unsigned short* __restrict__ KBF,
                                                  const unsigned short* __restrict__ CABF,
                                                  float* __restrict__ out) {
    __shared__ __align__(16) unsigned short lsA[2][4096];
    __shared__ __align__(16) unsigned short lsB[2][4096];
    const int r = 31 - (blockIdx.x >> 5);
    const int bm = blockIdx.x & 31;
    const int t = threadIdx.x, w = t >> 6, l = t & 63;
    const int wr = w >> 1, wc = w & 1;
    const int m0 = bm * 128;
    const int rowA0 = w * 32 + (l >> 2);
    const int scol8 = ((l & 3) ^ ((l >> 3) & 3)) * 8;
    const int rsw   = ((l >> 4) ^ ((l >> 1) & 3)) * 8;
    const int wvb = w * 1024;
    const int NS = 4 * r + 8;

    f32x4 acc[4][4];
#pragma unroll
    for (int a = 0; a < 4; ++a)
#pragma unroll
        for (int c = 0; c < 4; ++c) acc[a][c] = (f32x4)(0.f);

#define STAGE3(q, buf) do {                                                            \
    const unsigned short *ga, *gb;  int strA, strB;                                    \
    if ((q) < 4 * (r + 1)) {                                                           \
        ga = UBF + (size_t)(m0 + rowA0) * KFULL + (q) * 32 + scol8;  strA = KFULL;     \
        gb = KBF + (size_t)(r - ((q) >> 2)) * 16384 + rowA0 * 128                      \
             + ((q) & 3) * 32 + scol8;                               strB = 128;       \
    } else {                                                                           \
        ga = SBF + (size_t)(m0 + rowA0) * 128 + ((q) & 3) * 32 + scol8;  strA = 128;   \
        gb = CABF + (size_t)(r + 1) * 16384 + rowA0 * 128 + ((q) & 3) * 32 + scol8;    \
        strB = 128;                                                                    \
    }                                                                                  \
    gld16(ga, &lsA[buf][wvb]);  gld16(ga + 16 * strA, &lsA[buf][wvb + 512]);           \
    gld16(gb, &lsB[buf][wvb]);  gld16(gb + 16 * strB, &lsB[buf][wvb + 512]);           \
} while (0)

    STAGE3(0, 0);
    __syncthreads();
#pragma unroll 1
    for (int q = 0; q < NS; ++q) {
        const int buf = q & 1;
        if (q + 1 < NS) STAGE3(q + 1, buf ^ 1);
        s16x8 af[4], bfr[4];
#pragma unroll
        for (int mi = 0; mi < 4; ++mi)
            af[mi] = *(const s16x8*)(&lsA[buf][(wr * 64 + mi * 16 + (l & 15)) * 32 + rsw]);
#pragma unroll
        for (int ni = 0; ni < 4; ++ni)
            bfr[ni] = *(const s16x8*)(&lsB[buf][(wc * 64 + ni * 16 + (l & 15)) * 32 + rsw]);
#pragma unroll
        for (int mi = 0; mi < 4; ++mi)
#pragma unroll
            for (int ni = 0; ni < 4; ++ni)
                acc[mi][ni] = __builtin_amdgcn_mfma_f32_16x16x32_bf16(af[mi], bfr[ni], acc[mi][ni], 0, 0, 0);
        __syncthreads();
    }
    const int row0 = wr * 64 + (l >> 4) * 4;
    const int col0 = wc * 64 + (l & 15);
#pragma unroll
    for (int mi = 0; mi < 4; ++mi)
#pragma unroll
        for (int ni = 0; ni < 4; ++ni)
#pragma unroll
            for (int jj = 0; jj < 4; ++jj)
                out[(size_t)(m0 + row0 + mi * 16 + jj) * KFULL + r * 128 + col0 + ni * 16] =
                    acc[mi][ni][jj];
#undef STAGE3
}

extern "C" void kernel_launch(void* const* d_in, const int* in_sizes, int n_in,
                              void* d_out, int out_size, void* d_ws, size_t ws_size,
                              hipStream_t stream) {
    const float* u  = (const float*)d_in[0];
    const float* Am = (const float*)d_in[1];
    const float* Bm = (const float*)d_in[2];
    const float* Cm = (const float*)d_in[3];
    const float* Dm = (const float*)d_in[4];
    float* out = (float*)d_out;
    float* wsf = (float*)d_ws;

    unsigned short* UBF  = (unsigned short*)(wsf + OFF_UBF);
    unsigned short* SBF  = (unsigned short*)(wsf + OFF_SBF);
    unsigned short* KBF  = (unsigned short*)(wsf + OFF_KBF);
    unsigned short* CABF = (unsigned short*)(wsf + OFF_CABF);
    unsigned short* WBF  = (unsigned short*)(wsf + OFF_WBF);
    unsigned short* VBF  = (unsigned short*)(wsf + OFF_VBF);
    unsigned short* MCBF = (unsigned short*)(wsf + OFF_MCBF);
    float* VP2 = wsf + OFF_VP2;

    hipLaunchKernelGGL(k_init, dim3(8256), dim3(256), 0, stream, u, Am, Bm, Cm, Dm, wsf);

    // ---- 6-stage precompute via simultaneous doubling of A^d, CA[d]=C A^d, E[e]=A^e B
    MMDesc s;
    auto reset = [&s]() { for (int i = 0; i < 64; ++i) { s.ao[i] = -1; s.bo[i] = -1; s.bs[i] = 0; } };

    // S0: A2 ; CA1=C*A (dual) ; E1=A*B (dual, W col 30)
    reset(); s.n = 3;
    s.xo[0] = AP(1); s.yo[0] = AP(1); s.oo[0] = AP(2);
    s.xo[1] = OFF_C; s.yo[1] = AP(1); s.oo[1] = OFF_CA;
    s.bo[1] = CABF_U + 1 * 16384; s.bs[1] = 128;
    s.xo[2] = AP(1); s.yo[2] = OFF_B; s.oo[2] = OFF_W + 16384;
    s.bo[2] = WBF_U + 30 * 128; s.bs[2] = 4096;
    hipLaunchKernelGGL(k_mmb, dim3(12), dim3(256), 0, stream, wsf, s);

    // S1: A3, A4 ; CA2=CA1*A ; E2=A2*B, E3=A2*E1
    reset(); s.n = 5;
    s.xo[0] = AP(2); s.yo[0] = AP(1); s.oo[0] = AP(3);
    s.xo[1] = AP(2); s.yo[1] = AP(2); s.oo[1] = AP(4);
    s.xo[2] = OFF_CA; s.yo[2] = AP(1); s.oo[2] = OFF_CA + 16384;
    s.bo[2] = CABF_U + 2 * 16384; s.bs[2] = 128;
    s.xo[3] = AP(2); s.yo[3] = OFF_B; s.oo[3] = OFF_W + 2 * 16384;
    s.bo[3] = WBF_U + 29 * 128; s.bs[3] = 4096;
    s.xo[4] = AP(2); s.yo[4] = OFF_W + 16384; s.oo[4] = OFF_W + 3 * 16384;
    s.bo[4] = WBF_U + 28 * 128; s.bs[4] = 4096;
    hipLaunchKernelGGL(k_mmb, dim3(20), dim3(256), 0, stream, wsf, s);

    // S2: A5..A8 ; CA3..CA4 = CA1..2 * A2 ; E4..E7 = A4 * E0..3
    reset(); s.n = 10;
    for (int i = 0; i < 4; ++i) { s.xo[i] = AP(4); s.yo[i] = AP(1 + i); s.oo[i] = AP(5 + i); }
    for (int j = 0; j < 2; ++j) {
        s.xo[4 + j] = OFF_CA + j * 16384; s.yo[4 + j] = AP(2);
        s.oo[4 + j] = OFF_CA + (2 + j) * 16384;
        s.bo[4 + j] = CABF_U + (3 + j) * 16384; s.bs[4 + j] = 128;
    }
    for (int j = 0; j < 4; ++j) {
        s.xo[6 + j] = AP(4); s.yo[6 + j] = (j == 0) ? OFF_B : OFF_W + j * 16384;
        s.oo[6 + j] = OFF_W + (4 + j) * 16384;
        s.bo[6 + j] = WBF_U + (31 - (4 + j)) * 128; s.bs[6 + j] = 4096;
    }
    hipLaunchKernelGGL(k_mmb, dim3(40), dim3(256), 0, stream, wsf, s);

    // S3: A9..A16 ; CA5..8 = CA1..4 * A4 ; E8..15 = A8 * E0..7
    reset(); s.n = 20;
    for (int i = 0; i < 8; ++i) { s.xo[i] = AP(8); s.yo[i] = AP(1 + i); s.oo[i] = AP(9 + i); }
    for (int j = 0; j < 4; ++j) {
        s.xo[8 + j] = OFF_CA + j * 16384; s.yo[8 + j] = AP(4);
        s.oo[8 + j] = OFF_CA + (4 + j) * 16384;
        s.bo[8 + j] = CABF_U + (5 + j) * 16384; s.bs[8 + j] = 128;
    }
    for (int j = 0; j < 8; ++j) {
        s.xo[12 + j] = AP(8); s.yo[12 + j] = (j == 0) ? OFF_B : OFF_W + j * 16384;
        s.oo[12 + j] = OFF_W + (8 + j) * 16384;
        s.bo[12 + j] = WBF_U + (31 - (8 + j)) * 128; s.bs[12 + j] = 4096;
    }
    hipLaunchKernelGGL(k_mmb, dim3(80), dim3(256), 0, stream, wsf, s);

    // S4: A17..A32 ; CA9..16 = CA1..8 * A8 ; E16..31 = A16 * E0..15
    reset(); s.n = 40;
    for (int i = 0; i < 16; ++i) { s.xo[i] = AP(16); s.yo[i] = AP(1 + i); s.oo[i] = AP(17 + i); }
    for (int j = 0; j < 8; ++j) {
        s.xo[16 + j] = OFF_CA + j * 16384; s.yo[16 + j] = AP(8);
        s.oo[16 + j] = OFF_CA + (8 + j) * 16384;
        s.bo[16 + j] = CABF_U + (9 + j) * 16384; s.bs[16 + j] = 128;
    }
    for (int j = 0; j < 16; ++j) {
        s.xo[24 + j] = AP(16); s.yo[24 + j] = (j == 0) ? OFF_B : OFF_W + j * 16384;
        s.oo[24 + j] = OFF_W + (16 + j) * 16384;
        s.bo[24 + j] = WBF_U + (31 - (16 + j)) * 128; s.bs[24 + j] = 4096;
    }
    hipLaunchKernelGGL(k_mmb, dim3(160), dim3(256), 0, stream, wsf, s);

    // S5: K0..K31 = C*E (K0 +D, duals) ; CA17..32 = CA1..16 * A16 (duals) ; A64
    reset(); s.n = 49;
    for (int i = 0; i < 32; ++i) {
        s.xo[i] = OFF_C; s.yo[i] = (i == 0) ? OFF_B : OFF_W + i * 16384;
        s.oo[i] = OFF_K + i * 16384; s.ao[i] = (i == 0) ? OFF_D : -1;
        s.bo[i] = KBF_U + i * 16384; s.bs[i] = 128;
    }
    for (int j = 0; j < 16; ++j) {
        s.xo[32 + j] = OFF_CA + j * 16384; s.yo[32 + j] = AP(16);
        s.oo[32 + j] = OFF_CA + (16 + j) * 16384;
        s.bo[32 + j] = CABF_U + (17 + j) * 16384; s.bs[32 + j] = 128;
    }
    s.xo[48] = AP(32); s.yo[48] = AP(32); s.oo[48] = OFF_A64;
    hipLaunchKernelGGL(k_mmb, dim3(196), dim3(256), 0, stream, wsf, s);

    hipLaunchKernelGGL(k_castm2, dim3(64), dim3(256), 0, stream, wsf);
    hipLaunchKernelGGL(k_gemm1, dim3(128), dim3(256), 0, stream, UBF, WBF, VP2);
    hipLaunchKernelGGL(k_comb2, dim3(BATCH), dim3(256), 0, stream, VP2, MCBF, VBF, SBF);
    hipLaunchKernelGGL(k_gemm3, dim3(1024), dim3(256), 0, stream, UBF, SBF, KBF, CABF, out);
}